// Round 1
// baseline (917.160 us; speedup 1.0000x reference)
//
#include <hip/hip_runtime.h>

#define N_NODES  100000
#define N_EDGES  1600000
#define N_GRAPHS 256
#define F 64
#define NB_NODES 391   // ceil(100000/256)

// ---------------- degree / CSR build ----------------

__global__ void k_init(float* deg, int* cnt) {
    int i = blockIdx.x * 256 + threadIdx.x;
    if (i < N_NODES) { deg[i] = 1.0f; cnt[i] = 0; }  // 1.0 = self-loop weight
}

__global__ void k_edge_pass1(const int* __restrict__ dst, const float* __restrict__ ew,
                             float* deg, int* cnt) {
    int e = blockIdx.x * 256 + threadIdx.x;
    if (e < N_EDGES) {
        int d = dst[e];
        atomicAdd(&deg[d], ew[e]);
        atomicAdd(&cnt[d], 1);
    }
}

__global__ void k_dinv(float* deg) {
    int i = blockIdx.x * 256 + threadIdx.x;
    if (i < N_NODES) deg[i] = rsqrtf(deg[i]);  // deg >= 1 always (self-loop)
}

// exclusive scan of cnt -> row_off, 3-kernel hierarchical
__global__ void k_scan1(const int* __restrict__ cnt, int* row_off, int* bsum) {
    __shared__ int s[256];
    int tid = threadIdx.x;
    int i = blockIdx.x * 256 + tid;
    int v = (i < N_NODES) ? cnt[i] : 0;
    s[tid] = v;
    __syncthreads();
    int x = v;
    for (int off = 1; off < 256; off <<= 1) {
        int t = (tid >= off) ? s[tid - off] : 0;
        __syncthreads();
        x += t; s[tid] = x;
        __syncthreads();
    }
    if (i < N_NODES) row_off[i] = x - v;           // exclusive within block
    if (tid == 255) bsum[blockIdx.x] = x;          // block total
}

__global__ void k_scan2(const int* __restrict__ bsum, int* boff) {
    __shared__ int s[512];
    int tid = threadIdx.x;
    int v = (tid < NB_NODES) ? bsum[tid] : 0;
    s[tid] = v;
    __syncthreads();
    int x = v;
    for (int off = 1; off < 512; off <<= 1) {
        int t = (tid >= off) ? s[tid - off] : 0;
        __syncthreads();
        x += t; s[tid] = x;
        __syncthreads();
    }
    if (tid < NB_NODES) boff[tid] = x - v;         // exclusive block offsets
}

__global__ void k_scan3(int* row_off, const int* __restrict__ boff, int* cur) {
    int i = blockIdx.x * 256 + threadIdx.x;
    if (i < N_NODES) {
        int r = row_off[i] + boff[blockIdx.x];
        row_off[i] = r;
        cur[i] = r;
    }
    if (i == 0) row_off[N_NODES] = N_EDGES;
}

// scatter edges into CSR slots; ec = dinv[s]*ew*dinv[d] packed with src
__global__ void k_scatter(const int* __restrict__ src, const int* __restrict__ dst,
                          const float* __restrict__ ew, const float* __restrict__ dinv,
                          int* cur, int2* __restrict__ esec) {
    int e = blockIdx.x * 256 + threadIdx.x;
    if (e < N_EDGES) {
        int s = src[e], d = dst[e];
        int p = atomicAdd(&cur[d], 1);
        float c = dinv[s] * ew[e] * dinv[d];
        esec[p] = make_int2(s, __float_as_int(c));
    }
}

// ---------------- GEMM: H[N][64] = X[N][K] @ W[K][64] ----------------
// 32 nodes/block, 256 threads: lane=feat (0..63), grp=tid>>6; 8 nodes/thread.
template <int K>
__global__ __launch_bounds__(256) void k_gemm(const float* __restrict__ X,
                                              const float* __restrict__ W,
                                              float* __restrict__ H) {
    __shared__ float Ws[K * F];
    __shared__ float Xs[32][K];
    int tid = threadIdx.x;
    int nb = blockIdx.x * 32;
    for (int i = tid; i < K * F; i += 256) Ws[i] = W[i];
    for (int i = tid; i < 32 * K; i += 256) {
        int r = i / K, c = i % K;
        Xs[r][c] = X[(size_t)(nb + r) * K + c];
    }
    __syncthreads();
    int feat = tid & 63;
    int grp  = tid >> 6;
    float acc[8];
#pragma unroll
    for (int j = 0; j < 8; j++) acc[j] = 0.0f;
    for (int k = 0; k < K; k += 4) {
        float w0 = Ws[(k + 0) * F + feat];
        float w1 = Ws[(k + 1) * F + feat];
        float w2 = Ws[(k + 2) * F + feat];
        float w3 = Ws[(k + 3) * F + feat];
#pragma unroll
        for (int j = 0; j < 8; j++) {
            const float4 xv = *(const float4*)&Xs[grp + 4 * j][k];
            acc[j] = fmaf(xv.x, w0, acc[j]);
            acc[j] = fmaf(xv.y, w1, acc[j]);
            acc[j] = fmaf(xv.z, w2, acc[j]);
            acc[j] = fmaf(xv.w, w3, acc[j]);
        }
    }
#pragma unroll
    for (int j = 0; j < 8; j++)
        H[(size_t)(nb + grp + 4 * j) * F + feat] = acc[j];
}

// ---------------- aggregation: O = relu(b + dinv^2*H + sum_in ec*H[src]) ----------------
// one wave per node, lane = feature
__global__ __launch_bounds__(256) void k_agg(const float* __restrict__ H,
                                             const int* __restrict__ row_off,
                                             const int2* __restrict__ esec,
                                             const float* __restrict__ dinv,
                                             const float* __restrict__ bias,
                                             float* __restrict__ O) {
    int node = blockIdx.x * 4 + (threadIdx.x >> 6);
    int lane = threadIdx.x & 63;
    if (node >= N_NODES) return;
    int beg = row_off[node], end = row_off[node + 1];
    float di = dinv[node];
    float acc = bias[lane] + di * di * H[(size_t)node * F + lane];
    for (int j = beg; j < end; j++) {
        int2 v = esec[j];
        float c = __int_as_float(v.y);
        acc = fmaf(c, H[(size_t)v.x * F + lane], acc);
    }
    O[(size_t)node * F + lane] = fmaxf(acc, 0.0f);
}

// ---------------- graph boundaries via binary search (batch is sorted) ----------------
__global__ void k_gstart(const int* __restrict__ batch, int* gstart) {
    int g = blockIdx.x * 256 + threadIdx.x;
    if (g > N_GRAPHS) return;
    int lo = 0, hi = N_NODES;
    while (lo < hi) {
        int mid = (lo + hi) >> 1;
        if (batch[mid] < g) lo = mid + 1; else hi = mid;
    }
    gstart[g] = lo;
}

// ---------------- fused mean-pool + final linear ----------------
// one block (4 waves) per graph
__global__ __launch_bounds__(256) void k_pool_linear(const float* __restrict__ H,
                                                     const int* __restrict__ gstart,
                                                     const float* __restrict__ Wl,
                                                     const float* __restrict__ bl,
                                                     float* __restrict__ out) {
    int g = blockIdx.x;
    int beg = gstart[g], end = gstart[g + 1];
    int lane = threadIdx.x & 63, wv = threadIdx.x >> 6;
    float acc = 0.0f;
    for (int r = beg + wv; r < end; r += 4)
        acc += H[(size_t)r * F + lane];
    __shared__ float s[4][F];
    s[wv][lane] = acc;
    __syncthreads();
    if (wv == 0) {
        float tot = s[0][lane] + s[1][lane] + s[2][lane] + s[3][lane];
        float cntf = (float)(end - beg);
        float p = tot / fmaxf(cntf, 1.0f);
        for (int c = 0; c < 10; c++) {
            float v = p * Wl[lane * 10 + c];
            for (int off = 32; off; off >>= 1) v += __shfl_down(v, off);
            if (lane == 0) out[g * 10 + c] = v + bl[c];
        }
    }
}

// ---------------- launch ----------------

extern "C" void kernel_launch(void* const* d_in, const int* in_sizes, int n_in,
                              void* d_out, int out_size, void* d_ws, size_t ws_size,
                              hipStream_t stream) {
    const float* x    = (const float*)d_in[0];    // [N,128]
    const int*   ei   = (const int*)d_in[1];      // [2,E] -> src=ei, dst=ei+E
    const float* ea   = (const float*)d_in[2];    // [E]
    const int*   bat  = (const int*)d_in[3];      // [N] sorted
    const float* W1   = (const float*)d_in[4];
    const float* b1   = (const float*)d_in[5];
    const float* W2   = (const float*)d_in[6];
    const float* b2   = (const float*)d_in[7];
    const float* W3   = (const float*)d_in[8];
    const float* b3   = (const float*)d_in[9];
    const float* Wl   = (const float*)d_in[10];
    const float* bl   = (const float*)d_in[11];
    float* out = (float*)d_out;

    const int* src = ei;
    const int* dst = ei + N_EDGES;

    // carve workspace (256B aligned chunks)
    char* ws = (char*)d_ws;
    size_t off = 0;
    auto carve = [&](size_t bytes) {
        void* p = ws + off;
        off += (bytes + 255) & ~(size_t)255;
        return p;
    };
    float* deg     = (float*)carve(N_NODES * 4);        // becomes dinv after k_dinv
    int*   cnt     = (int*)  carve(N_NODES * 4);
    int*   row_off = (int*)  carve((N_NODES + 1) * 4);
    int*   bsum    = (int*)  carve(NB_NODES * 4);
    int*   boff    = (int*)  carve(NB_NODES * 4);
    int*   cur     = (int*)  carve(N_NODES * 4);
    int2*  esec    = (int2*) carve((size_t)N_EDGES * 8);
    float* hbuf    = (float*)carve((size_t)N_NODES * F * 4);
    float* obuf    = (float*)carve((size_t)N_NODES * F * 4);
    int*   gstart  = (int*)  carve((N_GRAPHS + 1) * 4);
    (void)ws_size; (void)in_sizes; (void)n_in; (void)out_size;

    const int EB = (N_EDGES + 255) / 256;  // 6250

    k_init<<<NB_NODES, 256, 0, stream>>>(deg, cnt);
    k_edge_pass1<<<EB, 256, 0, stream>>>(dst, ea, deg, cnt);
    k_dinv<<<NB_NODES, 256, 0, stream>>>(deg);
    k_scan1<<<NB_NODES, 256, 0, stream>>>(cnt, row_off, bsum);
    k_scan2<<<1, 512, 0, stream>>>(bsum, boff);
    k_scan3<<<NB_NODES, 256, 0, stream>>>(row_off, boff, cur);
    k_scatter<<<EB, 256, 0, stream>>>(src, dst, ea, deg, cur, esec);
    k_gstart<<<2, 256, 0, stream>>>(bat, gstart);

    // layer 1: K=128
    k_gemm<128><<<N_NODES / 32, 256, 0, stream>>>(x, W1, hbuf);
    k_agg<<<N_NODES / 4, 256, 0, stream>>>(hbuf, row_off, esec, deg, b1, obuf);
    // layer 2: K=64
    k_gemm<64><<<N_NODES / 32, 256, 0, stream>>>(obuf, W2, hbuf);
    k_agg<<<N_NODES / 4, 256, 0, stream>>>(hbuf, row_off, esec, deg, b2, obuf);
    // layer 3: K=64
    k_gemm<64><<<N_NODES / 32, 256, 0, stream>>>(obuf, W3, hbuf);
    k_agg<<<N_NODES / 4, 256, 0, stream>>>(hbuf, row_off, esec, deg, b3, obuf);

    k_pool_linear<<<N_GRAPHS, 256, 0, stream>>>(obuf, gstart, Wl, bl, out);
}

// Round 2
// 708.973 us; speedup vs baseline: 1.2936x; 1.2936x over previous
//
#include <hip/hip_runtime.h>

#define N_NODES  100000
#define N_EDGES  1600000
#define N_GRAPHS 256
#define F 64
#define NB_NODES 391   // ceil(100000/256)

// ---------------- degree / CSR build ----------------

__global__ void k_init(float* deg, int* cnt) {
    int i = blockIdx.x * 256 + threadIdx.x;
    if (i < N_NODES) { deg[i] = 1.0f; cnt[i] = 0; }  // 1.0 = self-loop weight
}

__global__ void k_edge_pass1(const int* __restrict__ dst, const float* __restrict__ ew,
                             float* deg, int* cnt) {
    int e = blockIdx.x * 256 + threadIdx.x;
    if (e < N_EDGES) {
        int d = dst[e];
        atomicAdd(&deg[d], ew[e]);
        atomicAdd(&cnt[d], 1);
    }
}

// exclusive scan of cnt -> row_off (block-local) ; also deg -> dinv (fused)
__global__ void k_scan1(const int* __restrict__ cnt, int* row_off, int* bsum, float* deg) {
    __shared__ int s[256];
    int tid = threadIdx.x;
    int i = blockIdx.x * 256 + tid;
    int v = (i < N_NODES) ? cnt[i] : 0;
    s[tid] = v;
    __syncthreads();
    int x = v;
    for (int off = 1; off < 256; off <<= 1) {
        int t = (tid >= off) ? s[tid - off] : 0;
        __syncthreads();
        x += t; s[tid] = x;
        __syncthreads();
    }
    if (i < N_NODES) {
        row_off[i] = x - v;                 // exclusive within block
        deg[i] = rsqrtf(deg[i]);            // deg >= 1 always (self-loop)
    }
    if (tid == 255) bsum[blockIdx.x] = x;   // block total
}

// block 0: scan of block sums; block 1: graph-boundary binary search
__global__ void k_scan2(const int* __restrict__ bsum, int* boff,
                        const int* __restrict__ batch, int* gstart) {
    if (blockIdx.x == 1) {
        int g = threadIdx.x;
        if (g > N_GRAPHS) return;
        int lo = 0, hi = N_NODES;
        while (lo < hi) {
            int mid = (lo + hi) >> 1;
            if (batch[mid] < g) lo = mid + 1; else hi = mid;
        }
        gstart[g] = lo;
        return;
    }
    __shared__ int s[512];
    int tid = threadIdx.x;
    int v = (tid < NB_NODES) ? bsum[tid] : 0;
    s[tid] = v;
    __syncthreads();
    int x = v;
    for (int off = 1; off < 512; off <<= 1) {
        int t = (tid >= off) ? s[tid - off] : 0;
        __syncthreads();
        x += t; s[tid] = x;
        __syncthreads();
    }
    if (tid < NB_NODES) boff[tid] = x - v;  // exclusive block offsets
}

__global__ void k_scan3(int* row_off, const int* __restrict__ boff, int* cur) {
    int i = blockIdx.x * 256 + threadIdx.x;
    if (i < N_NODES) {
        int r = row_off[i] + boff[blockIdx.x];
        row_off[i] = r;
        cur[i] = r;
    }
    if (i == 0) row_off[N_NODES] = N_EDGES;
}

// scatter edges into CSR slots; ec = dinv[s]*ew*dinv[d] packed with src
__global__ void k_scatter(const int* __restrict__ src, const int* __restrict__ dst,
                          const float* __restrict__ ew, const float* __restrict__ dinv,
                          int* cur, int2* __restrict__ esec) {
    int e = blockIdx.x * 256 + threadIdx.x;
    if (e < N_EDGES) {
        int s = src[e], d = dst[e];
        int p = atomicAdd(&cur[d], 1);
        float c = dinv[s] * ew[e] * dinv[d];
        esec[p] = make_int2(s, __float_as_int(c));
    }
}

// ---------------- GEMM: H[N][64] = X[N][K] @ W[K][64] ----------------
// 128 nodes/block, 256 threads. Thread = (ngrp 0..15, fgrp 0..15);
// each thread: 8 nodes (ngrp + 16*i, interleaved for bank-conflict-free Xs
// reads with pad 36) x 4 feats (fgrp*4). K staged in chunks of 32.
// 0.67 FMA per LDS byte (vs 0.22 in the old version).
template <int K>
__global__ __launch_bounds__(256) void k_gemm(const float* __restrict__ X,
                                              const float* __restrict__ W,
                                              float* __restrict__ H) {
    constexpr int KC = 32;
    constexpr int XP = KC + 4;            // 36-float row pitch: 4-bank skew per row
    __shared__ float Xs[128 * XP];
    __shared__ float Ws[KC * F];
    const int tid  = threadIdx.x;
    const int fgrp = tid & 15;
    const int ngrp = tid >> 4;
    const int f0   = fgrp * 4;
    const int nb   = blockIdx.x * 128;

    float acc[8][4];
#pragma unroll
    for (int i = 0; i < 8; i++)
#pragma unroll
        for (int j = 0; j < 4; j++) acc[i][j] = 0.0f;

    for (int kc = 0; kc < K; kc += KC) {
        if (kc) __syncthreads();
        // stage Xs: 128 rows x 32 floats, 4 float4 per thread
#pragma unroll
        for (int pass = 0; pass < 4; pass++) {
            int idx = tid + pass * 256;           // 0..1023 float4 slots
            int r = idx >> 3, q = idx & 7;
            int gr = nb + r; if (gr >= N_NODES) gr = N_NODES - 1;
            float4 v = *(const float4*)&X[(size_t)gr * K + kc + q * 4];
            *(float4*)&Xs[r * XP + q * 4] = v;
        }
        // stage Ws: 32 x 64 floats, 2 float4 per thread
#pragma unroll
        for (int pass = 0; pass < 2; pass++) {
            int idx = tid + pass * 256;           // 0..511 float4 slots
            float4 v = *(const float4*)&W[(size_t)(kc + (idx >> 4)) * F + (idx & 15) * 4];
            *(float4*)&Ws[idx * 4] = v;
        }
        __syncthreads();
#pragma unroll
        for (int k = 0; k < KC; k += 4) {
            float4 wv[4];
#pragma unroll
            for (int kk = 0; kk < 4; kk++)
                wv[kk] = *(const float4*)&Ws[(k + kk) * F + f0];
#pragma unroll
            for (int i = 0; i < 8; i++) {
                float4 xv = *(const float4*)&Xs[(ngrp + 16 * i) * XP + k];
                acc[i][0] = fmaf(xv.x, wv[0].x, acc[i][0]);
                acc[i][0] = fmaf(xv.y, wv[1].x, acc[i][0]);
                acc[i][0] = fmaf(xv.z, wv[2].x, acc[i][0]);
                acc[i][0] = fmaf(xv.w, wv[3].x, acc[i][0]);
                acc[i][1] = fmaf(xv.x, wv[0].y, acc[i][1]);
                acc[i][1] = fmaf(xv.y, wv[1].y, acc[i][1]);
                acc[i][1] = fmaf(xv.z, wv[2].y, acc[i][1]);
                acc[i][1] = fmaf(xv.w, wv[3].y, acc[i][1]);
                acc[i][2] = fmaf(xv.x, wv[0].z, acc[i][2]);
                acc[i][2] = fmaf(xv.y, wv[1].z, acc[i][2]);
                acc[i][2] = fmaf(xv.z, wv[2].z, acc[i][2]);
                acc[i][2] = fmaf(xv.w, wv[3].z, acc[i][2]);
                acc[i][3] = fmaf(xv.x, wv[0].w, acc[i][3]);
                acc[i][3] = fmaf(xv.y, wv[1].w, acc[i][3]);
                acc[i][3] = fmaf(xv.z, wv[2].w, acc[i][3]);
                acc[i][3] = fmaf(xv.w, wv[3].w, acc[i][3]);
            }
        }
    }
#pragma unroll
    for (int i = 0; i < 8; i++) {
        int gn = nb + ngrp + 16 * i;
        if (gn < N_NODES)
            *(float4*)&H[(size_t)gn * F + f0] =
                make_float4(acc[i][0], acc[i][1], acc[i][2], acc[i][3]);
    }
}

// ---------------- aggregation: O = relu(b + dinv^2*H + sum_in ec*H[src]) ----------------
// one wave per node, lane = feature. 8-wide predicated unroll: 8 independent
// H-gathers in flight per wave (the baseline had 1 -> latency-bound at 150us).
__global__ __launch_bounds__(256) void k_agg(const float* __restrict__ H,
                                             const int* __restrict__ row_off,
                                             const int2* __restrict__ esec,
                                             const float* __restrict__ dinv,
                                             const float* __restrict__ bias,
                                             float* __restrict__ O) {
    int node = blockIdx.x * 4 + (threadIdx.x >> 6);
    int lane = threadIdx.x & 63;
    if (node >= N_NODES) return;
    int beg = row_off[node], end = row_off[node + 1];
    float di = dinv[node];
    const float* Hl = H + lane;
    float base = bias[lane] + di * di * Hl[(size_t)node * F];
    float a[8];
#pragma unroll
    for (int u = 0; u < 8; u++) a[u] = 0.0f;
    const long long* ep = (const long long*)esec;
    for (int j = beg; j < end; j += 8) {
#pragma unroll
        for (int u = 0; u < 8; u++) {
            int jj = j + u;
            int jc = jj < end ? jj : end - 1;          // clamp (end>beg here)
            long long raw = __builtin_nontemporal_load(&ep[jc]);
            int   s = (int)raw;
            float c = (jj < end) ? __int_as_float((int)(raw >> 32)) : 0.0f;
            a[u] = fmaf(c, Hl[(size_t)s * F], a[u]);
        }
    }
    float acc = base + (((a[0] + a[1]) + (a[2] + a[3])) + ((a[4] + a[5]) + (a[6] + a[7])));
    O[(size_t)node * F + lane] = fmaxf(acc, 0.0f);
}

// ---------------- fused mean-pool + final linear ----------------
__global__ __launch_bounds__(256) void k_pool_linear(const float* __restrict__ H,
                                                     const int* __restrict__ gstart,
                                                     const float* __restrict__ Wl,
                                                     const float* __restrict__ bl,
                                                     float* __restrict__ out) {
    int g = blockIdx.x;
    int beg = gstart[g], end = gstart[g + 1];
    int lane = threadIdx.x & 63, wv = threadIdx.x >> 6;
    float acc = 0.0f;
    for (int r = beg + wv; r < end; r += 4)
        acc += H[(size_t)r * F + lane];
    __shared__ float s[4][F];
    s[wv][lane] = acc;
    __syncthreads();
    if (wv == 0) {
        float tot = s[0][lane] + s[1][lane] + s[2][lane] + s[3][lane];
        float cntf = (float)(end - beg);
        float p = tot / fmaxf(cntf, 1.0f);
        for (int c = 0; c < 10; c++) {
            float v = p * Wl[lane * 10 + c];
            for (int off = 32; off; off >>= 1) v += __shfl_down(v, off);
            if (lane == 0) out[g * 10 + c] = v + bl[c];
        }
    }
}

// ---------------- launch ----------------

extern "C" void kernel_launch(void* const* d_in, const int* in_sizes, int n_in,
                              void* d_out, int out_size, void* d_ws, size_t ws_size,
                              hipStream_t stream) {
    const float* x    = (const float*)d_in[0];    // [N,128]
    const int*   ei   = (const int*)d_in[1];      // [2,E] -> src=ei, dst=ei+E
    const float* ea   = (const float*)d_in[2];    // [E]
    const int*   bat  = (const int*)d_in[3];      // [N] sorted
    const float* W1   = (const float*)d_in[4];
    const float* b1   = (const float*)d_in[5];
    const float* W2   = (const float*)d_in[6];
    const float* b2   = (const float*)d_in[7];
    const float* W3   = (const float*)d_in[8];
    const float* b3   = (const float*)d_in[9];
    const float* Wl   = (const float*)d_in[10];
    const float* bl   = (const float*)d_in[11];
    float* out = (float*)d_out;

    const int* src = ei;
    const int* dst = ei + N_EDGES;

    char* ws = (char*)d_ws;
    size_t off = 0;
    auto carve = [&](size_t bytes) {
        void* p = ws + off;
        off += (bytes + 255) & ~(size_t)255;
        return p;
    };
    float* deg     = (float*)carve(N_NODES * 4);        // becomes dinv in k_scan1
    int*   cnt     = (int*)  carve(N_NODES * 4);
    int*   row_off = (int*)  carve((N_NODES + 1) * 4);
    int*   bsum    = (int*)  carve(NB_NODES * 4);
    int*   boff    = (int*)  carve(NB_NODES * 4);
    int*   cur     = (int*)  carve(N_NODES * 4);
    int2*  esec    = (int2*) carve((size_t)N_EDGES * 8);
    float* hbuf    = (float*)carve((size_t)N_NODES * F * 4);
    float* obuf    = (float*)carve((size_t)N_NODES * F * 4);
    int*   gstart  = (int*)  carve((N_GRAPHS + 1) * 4);
    (void)ws_size; (void)in_sizes; (void)n_in; (void)out_size;

    const int EB = (N_EDGES + 255) / 256;  // 6250
    const int GB = (N_NODES + 127) / 128;  // 782

    k_init<<<NB_NODES, 256, 0, stream>>>(deg, cnt);
    k_edge_pass1<<<EB, 256, 0, stream>>>(dst, ea, deg, cnt);
    k_scan1<<<NB_NODES, 256, 0, stream>>>(cnt, row_off, bsum, deg);
    k_scan2<<<2, 512, 0, stream>>>(bsum, boff, bat, gstart);
    k_scan3<<<NB_NODES, 256, 0, stream>>>(row_off, boff, cur);
    k_scatter<<<EB, 256, 0, stream>>>(src, dst, ea, deg, cur, esec);

    // layer 1: K=128
    k_gemm<128><<<GB, 256, 0, stream>>>(x, W1, hbuf);
    k_agg<<<N_NODES / 4, 256, 0, stream>>>(hbuf, row_off, esec, deg, b1, obuf);
    // layer 2: K=64
    k_gemm<64><<<GB, 256, 0, stream>>>(obuf, W2, hbuf);
    k_agg<<<N_NODES / 4, 256, 0, stream>>>(hbuf, row_off, esec, deg, b2, obuf);
    // layer 3: K=64
    k_gemm<64><<<GB, 256, 0, stream>>>(obuf, W3, hbuf);
    k_agg<<<N_NODES / 4, 256, 0, stream>>>(hbuf, row_off, esec, deg, b3, obuf);

    k_pool_linear<<<N_GRAPHS, 256, 0, stream>>>(obuf, gstart, Wl, bl, out);
}

// Round 3
// 554.740 us; speedup vs baseline: 1.6533x; 1.2780x over previous
//
#include <hip/hip_runtime.h>

#define N_NODES  100000
#define N_EDGES  1600000
#define N_GRAPHS 256
#define F 64
#define NBUCK  782   // ceil(N_NODES/128), bucket = dst >> 7
#define NCHUNK 782   // ceil(N_EDGES/2048), chunk = 2048 edges

// ======== atomic-free CSR build: two-level counting sort ========

// P1: per-chunk histogram over dst buckets (LDS atomics only)
__global__ __launch_bounds__(256) void k_hist(const int* __restrict__ dst, int* __restrict__ hist) {
    __shared__ int lh[NBUCK];
    int tid = threadIdx.x, chunk = blockIdx.x;
    for (int j = tid; j < NBUCK; j += 256) lh[j] = 0;
    __syncthreads();
    int e0 = chunk * 2048;
#pragma unroll
    for (int i = 0; i < 8; i++) {
        int e = e0 + i * 256 + tid;
        if (e < N_EDGES) atomicAdd(&lh[dst[e] >> 7], 1);
    }
    __syncthreads();
    for (int j = tid; j < NBUCK; j += 256) hist[chunk * NBUCK + j] = lh[j];
}

// P2: per-bucket column scan over chunks: hist[c][b] -> exclusive prefix; btot[b] = total
__global__ __launch_bounds__(256) void k_colscan(int* __restrict__ hist, int* __restrict__ btot) {
    __shared__ int ts[256];
    int b = blockIdx.x, tid = threadIdx.x;
    int v[4], loc[4], run = 0;
#pragma unroll
    for (int k = 0; k < 4; k++) {
        int c = tid * 4 + k;
        v[k] = (c < NCHUNK) ? hist[c * NBUCK + b] : 0;
        loc[k] = run; run += v[k];
    }
    ts[tid] = run;
    __syncthreads();
    int x = run;
    for (int off = 1; off < 256; off <<= 1) {
        int t = (tid >= off) ? ts[tid - off] : 0;
        __syncthreads();
        x += t; ts[tid] = x;
        __syncthreads();
    }
    int texcl = x - run;
#pragma unroll
    for (int k = 0; k < 4; k++) {
        int c = tid * 4 + k;
        if (c < NCHUNK) hist[c * NBUCK + b] = texcl + loc[k];
    }
    if (tid == 255) btot[b] = x;
}

// P3: scan bucket totals -> base[b]; base[NBUCK] = E
__global__ __launch_bounds__(256) void k_bscan(const int* __restrict__ btot, int* __restrict__ base) {
    __shared__ int ts[256];
    int tid = threadIdx.x;
    int v[4], loc[4], run = 0;
#pragma unroll
    for (int k = 0; k < 4; k++) {
        int c = tid * 4 + k;
        v[k] = (c < NBUCK) ? btot[c] : 0;
        loc[k] = run; run += v[k];
    }
    ts[tid] = run;
    __syncthreads();
    int x = run;
    for (int off = 1; off < 256; off <<= 1) {
        int t = (tid >= off) ? ts[tid - off] : 0;
        __syncthreads();
        x += t; ts[tid] = x;
        __syncthreads();
    }
    int texcl = x - run;
#pragma unroll
    for (int k = 0; k < 4; k++) {
        int c = tid * 4 + k;
        if (c < NBUCK) base[c] = texcl + loc[k];
    }
    if (tid == 255) base[NBUCK] = x;   // == N_EDGES
}

// P4: partition edges into bucket-contiguous records (src | d7<<17, ew). LDS cursors, no global atomics.
__global__ __launch_bounds__(256) void k_partition(const int* __restrict__ src, const int* __restrict__ dst,
                                                   const float* __restrict__ ew,
                                                   const int* __restrict__ hist, const int* __restrict__ base,
                                                   long long* __restrict__ part) {
    __shared__ int cursor[NBUCK];
    int tid = threadIdx.x, chunk = blockIdx.x;
    for (int j = tid; j < NBUCK; j += 256) cursor[j] = base[j] + hist[chunk * NBUCK + j];
    __syncthreads();
    int e0 = chunk * 2048;
#pragma unroll
    for (int i = 0; i < 8; i++) {
        int e = e0 + i * 256 + tid;
        if (e < N_EDGES) {
            int d = dst[e];
            int pos = atomicAdd(&cursor[d >> 7], 1);   // LDS atomic: unique rank
            unsigned lo = (unsigned)src[e] | ((unsigned)(d & 127) << 17);
            long long rec = (long long)((unsigned long long)lo |
                            ((unsigned long long)__float_as_uint(ew[e]) << 32));
            part[pos] = rec;
        }
    }
}

// P5: per-bucket: deg (LDS float atomics) -> dinv, cnt -> row_off, scatter esec=(src, ew*dinv[d])
__global__ __launch_bounds__(256) void k_bucket(const long long* __restrict__ part,
                                                const int* __restrict__ base,
                                                float* __restrict__ dinv_g, int* __restrict__ row_off,
                                                int2* __restrict__ esec) {
    __shared__ float fdeg[128];
    __shared__ float sdinv[128];
    __shared__ int   cnt[128];
    __shared__ int   sc[128];
    __shared__ int   cursor[128];
    int b = blockIdx.x, tid = threadIdx.x;
    if (tid < 128) { fdeg[tid] = 1.0f; cnt[tid] = 0; }   // 1.0 = self-loop weight
    __syncthreads();
    int e0 = base[b], e1 = base[b + 1], ne = e1 - e0;
    for (int k = tid; k < ne; k += 256) {
        long long rec = part[e0 + k];
        int lo = (int)rec;
        int d7 = lo >> 17;                                // src < 2^17 so this is exact
        atomicAdd(&fdeg[d7], __uint_as_float((unsigned)(rec >> 32)));
        atomicAdd(&cnt[d7], 1);
    }
    __syncthreads();
    int myc = 0, x = 0;
    if (tid < 128) {
        float dv = rsqrtf(fdeg[tid]);
        sdinv[tid] = dv;
        int node = b * 128 + tid;
        if (node < N_NODES) dinv_g[node] = dv;
        myc = cnt[tid]; x = myc; sc[tid] = x;
    }
    __syncthreads();
    for (int off = 1; off < 128; off <<= 1) {
        int t = (tid < 128 && tid >= off) ? sc[tid - off] : 0;
        __syncthreads();
        if (tid < 128) { x += t; sc[tid] = x; }
        __syncthreads();
    }
    if (tid < 128) {
        int excl = x - myc;
        int node = b * 128 + tid;
        if (node < N_NODES) row_off[node] = e0 + excl;
        cursor[tid] = e0 + excl;
    }
    if (b == 0 && tid == 0) row_off[N_NODES] = N_EDGES;
    __syncthreads();
    for (int k = tid; k < ne; k += 256) {
        long long rec = part[e0 + k];
        int lo = (int)rec;
        int d7 = lo >> 17;
        float w = __uint_as_float((unsigned)(rec >> 32));
        int pos = atomicAdd(&cursor[d7], 1);
        esec[pos] = make_int2(lo & 0x1FFFF, __float_as_int(w * sdinv[d7]));
    }
}

// P6: multiply in dinv[src]
__global__ __launch_bounds__(256) void k_coef(int2* __restrict__ esec, const float* __restrict__ dinv_g) {
    int e = blockIdx.x * 256 + threadIdx.x;
    if (e < N_EDGES) {
        int2 v = esec[e];
        esec[e] = make_int2(v.x, __float_as_int(__int_as_float(v.y) * dinv_g[v.x]));
    }
}

// graph boundaries via binary search (batch is sorted)
__global__ void k_gstart(const int* __restrict__ batch, int* gstart) {
    int g = blockIdx.x * 256 + threadIdx.x;
    if (g > N_GRAPHS) return;
    int lo = 0, hi = N_NODES;
    while (lo < hi) {
        int mid = (lo + hi) >> 1;
        if (batch[mid] < g) lo = mid + 1; else hi = mid;
    }
    gstart[g] = lo;
}

// ---------------- GEMM: H[N][64] = X[N][K] @ W[K][64] ----------------
template <int K>
__global__ __launch_bounds__(256) void k_gemm(const float* __restrict__ X,
                                              const float* __restrict__ W,
                                              float* __restrict__ H) {
    constexpr int KC = 32;
    constexpr int XP = KC + 4;
    __shared__ float Xs[128 * XP];
    __shared__ float Ws[KC * F];
    const int tid  = threadIdx.x;
    const int fgrp = tid & 15;
    const int ngrp = tid >> 4;
    const int f0   = fgrp * 4;
    const int nb   = blockIdx.x * 128;

    float acc[8][4];
#pragma unroll
    for (int i = 0; i < 8; i++)
#pragma unroll
        for (int j = 0; j < 4; j++) acc[i][j] = 0.0f;

    for (int kc = 0; kc < K; kc += KC) {
        if (kc) __syncthreads();
#pragma unroll
        for (int pass = 0; pass < 4; pass++) {
            int idx = tid + pass * 256;
            int r = idx >> 3, q = idx & 7;
            int gr = nb + r; if (gr >= N_NODES) gr = N_NODES - 1;
            float4 v = *(const float4*)&X[(size_t)gr * K + kc + q * 4];
            *(float4*)&Xs[r * XP + q * 4] = v;
        }
#pragma unroll
        for (int pass = 0; pass < 2; pass++) {
            int idx = tid + pass * 256;
            float4 v = *(const float4*)&W[(size_t)(kc + (idx >> 4)) * F + (idx & 15) * 4];
            *(float4*)&Ws[idx * 4] = v;
        }
        __syncthreads();
#pragma unroll
        for (int k = 0; k < KC; k += 4) {
            float4 wv[4];
#pragma unroll
            for (int kk = 0; kk < 4; kk++)
                wv[kk] = *(const float4*)&Ws[(k + kk) * F + f0];
#pragma unroll
            for (int i = 0; i < 8; i++) {
                float4 xv = *(const float4*)&Xs[(ngrp + 16 * i) * XP + k];
                acc[i][0] = fmaf(xv.x, wv[0].x, acc[i][0]);
                acc[i][0] = fmaf(xv.y, wv[1].x, acc[i][0]);
                acc[i][0] = fmaf(xv.z, wv[2].x, acc[i][0]);
                acc[i][0] = fmaf(xv.w, wv[3].x, acc[i][0]);
                acc[i][1] = fmaf(xv.x, wv[0].y, acc[i][1]);
                acc[i][1] = fmaf(xv.y, wv[1].y, acc[i][1]);
                acc[i][1] = fmaf(xv.z, wv[2].y, acc[i][1]);
                acc[i][1] = fmaf(xv.w, wv[3].y, acc[i][1]);
                acc[i][2] = fmaf(xv.x, wv[0].z, acc[i][2]);
                acc[i][2] = fmaf(xv.y, wv[1].z, acc[i][2]);
                acc[i][2] = fmaf(xv.z, wv[2].z, acc[i][2]);
                acc[i][2] = fmaf(xv.w, wv[3].z, acc[i][2]);
                acc[i][3] = fmaf(xv.x, wv[0].w, acc[i][3]);
                acc[i][3] = fmaf(xv.y, wv[1].w, acc[i][3]);
                acc[i][3] = fmaf(xv.z, wv[2].w, acc[i][3]);
                acc[i][3] = fmaf(xv.w, wv[3].w, acc[i][3]);
            }
        }
    }
#pragma unroll
    for (int i = 0; i < 8; i++) {
        int gn = nb + ngrp + 16 * i;
        if (gn < N_NODES)
            *(float4*)&H[(size_t)gn * F + f0] =
                make_float4(acc[i][0], acc[i][1], acc[i][2], acc[i][3]);
    }
}

// ---------------- aggregation: O = relu(b + dinv^2*H + sum_in ec*H[src]) ----------------
__global__ __launch_bounds__(256) void k_agg(const float* __restrict__ H,
                                             const int* __restrict__ row_off,
                                             const int2* __restrict__ esec,
                                             const float* __restrict__ dinv,
                                             const float* __restrict__ bias,
                                             float* __restrict__ O) {
    int node = blockIdx.x * 4 + (threadIdx.x >> 6);
    int lane = threadIdx.x & 63;
    if (node >= N_NODES) return;
    int beg = row_off[node], end = row_off[node + 1];
    float di = dinv[node];
    const float* Hl = H + lane;
    float base = bias[lane] + di * di * Hl[(size_t)node * F];
    float a[8];
#pragma unroll
    for (int u = 0; u < 8; u++) a[u] = 0.0f;
    const long long* ep = (const long long*)esec;
    for (int j = beg; j < end; j += 8) {
#pragma unroll
        for (int u = 0; u < 8; u++) {
            int jj = j + u;
            int jc = jj < end ? jj : end - 1;
            long long raw = __builtin_nontemporal_load(&ep[jc]);
            int   s = (int)raw;
            float c = (jj < end) ? __int_as_float((int)(raw >> 32)) : 0.0f;
            a[u] = fmaf(c, Hl[(size_t)s * F], a[u]);
        }
    }
    float acc = base + (((a[0] + a[1]) + (a[2] + a[3])) + ((a[4] + a[5]) + (a[6] + a[7])));
    O[(size_t)node * F + lane] = fmaxf(acc, 0.0f);
}

// ---------------- fused mean-pool + final linear ----------------
__global__ __launch_bounds__(256) void k_pool_linear(const float* __restrict__ H,
                                                     const int* __restrict__ gstart,
                                                     const float* __restrict__ Wl,
                                                     const float* __restrict__ bl,
                                                     float* __restrict__ out) {
    int g = blockIdx.x;
    int beg = gstart[g], end = gstart[g + 1];
    int lane = threadIdx.x & 63, wv = threadIdx.x >> 6;
    float acc = 0.0f;
    for (int r = beg + wv; r < end; r += 4)
        acc += H[(size_t)r * F + lane];
    __shared__ float s[4][F];
    s[wv][lane] = acc;
    __syncthreads();
    if (wv == 0) {
        float tot = s[0][lane] + s[1][lane] + s[2][lane] + s[3][lane];
        float cntf = (float)(end - beg);
        float p = tot / fmaxf(cntf, 1.0f);
        for (int c = 0; c < 10; c++) {
            float v = p * Wl[lane * 10 + c];
            for (int off = 32; off; off >>= 1) v += __shfl_down(v, off);
            if (lane == 0) out[g * 10 + c] = v + bl[c];
        }
    }
}

// ---------------- launch ----------------

extern "C" void kernel_launch(void* const* d_in, const int* in_sizes, int n_in,
                              void* d_out, int out_size, void* d_ws, size_t ws_size,
                              hipStream_t stream) {
    const float* x    = (const float*)d_in[0];
    const int*   ei   = (const int*)d_in[1];
    const float* ea   = (const float*)d_in[2];
    const int*   bat  = (const int*)d_in[3];
    const float* W1   = (const float*)d_in[4];
    const float* b1   = (const float*)d_in[5];
    const float* W2   = (const float*)d_in[6];
    const float* b2   = (const float*)d_in[7];
    const float* W3   = (const float*)d_in[8];
    const float* b3   = (const float*)d_in[9];
    const float* Wl   = (const float*)d_in[10];
    const float* bl   = (const float*)d_in[11];
    float* out = (float*)d_out;

    const int* src = ei;
    const int* dst = ei + N_EDGES;

    char* ws = (char*)d_ws;
    size_t off = 0;
    auto carve = [&](size_t bytes) {
        void* p = ws + off;
        off += (bytes + 255) & ~(size_t)255;
        return p;
    };
    float* dinv    = (float*)carve(N_NODES * 4);
    int*   row_off = (int*)  carve((N_NODES + 1) * 4);
    int2*  esec    = (int2*) carve((size_t)N_EDGES * 8);
    float* hbuf    = (float*)carve((size_t)N_NODES * F * 4);   // build scratch aliases here
    float* obuf    = (float*)carve((size_t)N_NODES * F * 4);
    int*   gstart  = (int*)  carve((N_GRAPHS + 1) * 4);
    (void)ws_size; (void)in_sizes; (void)n_in; (void)out_size;

    // build-phase scratch aliased onto hbuf (dead before first GEMM writes hbuf)
    long long* part = (long long*)hbuf;                              // 12.8 MB
    int*       hist = (int*)((char*)hbuf + (size_t)N_EDGES * 8);     // 2.45 MB
    int*       btot = (int*)((char*)hist + (size_t)NCHUNK * NBUCK * 4);
    int*       base = (int*)((char*)btot + (NBUCK + 8) * 4);

    const int EB = (N_EDGES + 255) / 256;  // 6250
    const int GB = (N_NODES + 127) / 128;  // 782

    k_hist     <<<NCHUNK, 256, 0, stream>>>(dst, hist);
    k_colscan  <<<NBUCK,  256, 0, stream>>>(hist, btot);
    k_bscan    <<<1,      256, 0, stream>>>(btot, base);
    k_partition<<<NCHUNK, 256, 0, stream>>>(src, dst, ea, hist, base, part);
    k_bucket   <<<NBUCK,  256, 0, stream>>>(part, base, dinv, row_off, esec);
    k_coef     <<<EB,     256, 0, stream>>>(esec, dinv);
    k_gstart   <<<2,      256, 0, stream>>>(bat, gstart);

    k_gemm<128><<<GB, 256, 0, stream>>>(x, W1, hbuf);
    k_agg<<<N_NODES / 4, 256, 0, stream>>>(hbuf, row_off, esec, dinv, b1, obuf);
    k_gemm<64><<<GB, 256, 0, stream>>>(obuf, W2, hbuf);
    k_agg<<<N_NODES / 4, 256, 0, stream>>>(hbuf, row_off, esec, dinv, b2, obuf);
    k_gemm<64><<<GB, 256, 0, stream>>>(obuf, W3, hbuf);
    k_agg<<<N_NODES / 4, 256, 0, stream>>>(hbuf, row_off, esec, dinv, b3, obuf);

    k_pool_linear<<<N_GRAPHS, 256, 0, stream>>>(obuf, gstart, Wl, bl, out);
}

// Round 5
// 421.436 us; speedup vs baseline: 2.1763x; 1.3163x over previous
//
#include <hip/hip_runtime.h>
#include <hip/hip_bf16.h>

#define N_NODES  100000
#define N_EDGES  1600000
#define N_GRAPHS 256
#define F 64
#define NBUCK  782   // ceil(N_NODES/128), bucket = dst >> 7
#define NCHUNK 782   // ceil(N_EDGES/2048), chunk = 2048 edges

// ======== atomic-free CSR build: two-level counting sort (round-3 proven) ========

__global__ __launch_bounds__(256) void k_hist(const int* __restrict__ dst, int* __restrict__ hist) {
    __shared__ int lh[NBUCK];
    int tid = threadIdx.x, chunk = blockIdx.x;
    for (int j = tid; j < NBUCK; j += 256) lh[j] = 0;
    __syncthreads();
    int e0 = chunk * 2048;
#pragma unroll
    for (int i = 0; i < 8; i++) {
        int e = e0 + i * 256 + tid;
        if (e < N_EDGES) atomicAdd(&lh[dst[e] >> 7], 1);
    }
    __syncthreads();
    for (int j = tid; j < NBUCK; j += 256) hist[chunk * NBUCK + j] = lh[j];
}

__global__ __launch_bounds__(256) void k_colscan(int* __restrict__ hist, int* __restrict__ btot) {
    __shared__ int ts[256];
    int b = blockIdx.x, tid = threadIdx.x;
    int v[4], loc[4], run = 0;
#pragma unroll
    for (int k = 0; k < 4; k++) {
        int c = tid * 4 + k;
        v[k] = (c < NCHUNK) ? hist[c * NBUCK + b] : 0;
        loc[k] = run; run += v[k];
    }
    ts[tid] = run;
    __syncthreads();
    int x = run;
    for (int off = 1; off < 256; off <<= 1) {
        int t = (tid >= off) ? ts[tid - off] : 0;
        __syncthreads();
        x += t; ts[tid] = x;
        __syncthreads();
    }
    int texcl = x - run;
#pragma unroll
    for (int k = 0; k < 4; k++) {
        int c = tid * 4 + k;
        if (c < NCHUNK) hist[c * NBUCK + b] = texcl + loc[k];
    }
    if (tid == 255) btot[b] = x;
}

__global__ __launch_bounds__(256) void k_bscan(const int* __restrict__ btot, int* __restrict__ base) {
    __shared__ int ts[256];
    int tid = threadIdx.x;
    int v[4], loc[4], run = 0;
#pragma unroll
    for (int k = 0; k < 4; k++) {
        int c = tid * 4 + k;
        v[k] = (c < NBUCK) ? btot[c] : 0;
        loc[k] = run; run += v[k];
    }
    ts[tid] = run;
    __syncthreads();
    int x = run;
    for (int off = 1; off < 256; off <<= 1) {
        int t = (tid >= off) ? ts[tid - off] : 0;
        __syncthreads();
        x += t; ts[tid] = x;
        __syncthreads();
    }
    int texcl = x - run;
#pragma unroll
    for (int k = 0; k < 4; k++) {
        int c = tid * 4 + k;
        if (c < NBUCK) base[c] = texcl + loc[k];
    }
    if (tid == 255) base[NBUCK] = x;
}

__global__ __launch_bounds__(256) void k_partition(const int* __restrict__ src, const int* __restrict__ dst,
                                                   const float* __restrict__ ew,
                                                   const int* __restrict__ hist, const int* __restrict__ base,
                                                   long long* __restrict__ part) {
    __shared__ int cursor[NBUCK];
    int tid = threadIdx.x, chunk = blockIdx.x;
    for (int j = tid; j < NBUCK; j += 256) cursor[j] = base[j] + hist[chunk * NBUCK + j];
    __syncthreads();
    int e0 = chunk * 2048;
#pragma unroll
    for (int i = 0; i < 8; i++) {
        int e = e0 + i * 256 + tid;
        if (e < N_EDGES) {
            int d = dst[e];
            int pos = atomicAdd(&cursor[d >> 7], 1);
            unsigned lo = (unsigned)src[e] | ((unsigned)(d & 127) << 17);
            long long rec = (long long)((unsigned long long)lo |
                            ((unsigned long long)__float_as_uint(ew[e]) << 32));
            part[pos] = rec;
        }
    }
}

// per-bucket: deg (LDS atomics) -> dinv, cnt -> row_off, scatter esec=(src*128, ew*dinv[d])
__global__ __launch_bounds__(256) void k_bucket(const long long* __restrict__ part,
                                                const int* __restrict__ base,
                                                float* __restrict__ dinv_g, int* __restrict__ row_off,
                                                int2* __restrict__ esec) {
    __shared__ float fdeg[128];
    __shared__ float sdinv[128];
    __shared__ int   cnt[128];
    __shared__ int   sc[128];
    __shared__ int   cursor[128];
    int b = blockIdx.x, tid = threadIdx.x;
    if (tid < 128) { fdeg[tid] = 1.0f; cnt[tid] = 0; }   // 1.0 = self-loop weight
    __syncthreads();
    int e0 = base[b], e1 = base[b + 1], ne = e1 - e0;
    for (int k = tid; k < ne; k += 256) {
        long long rec = part[e0 + k];
        int lo = (int)rec;
        int d7 = (lo >> 17) & 127;
        atomicAdd(&fdeg[d7], __uint_as_float((unsigned)(rec >> 32)));
        atomicAdd(&cnt[d7], 1);
    }
    __syncthreads();
    int myc = 0, x = 0;
    if (tid < 128) {
        float dv = rsqrtf(fdeg[tid]);
        sdinv[tid] = dv;
        int node = b * 128 + tid;
        if (node < N_NODES) dinv_g[node] = dv;
        myc = cnt[tid]; x = myc; sc[tid] = x;
    }
    __syncthreads();
    for (int off = 1; off < 128; off <<= 1) {
        int t = (tid < 128 && tid >= off) ? sc[tid - off] : 0;
        __syncthreads();
        if (tid < 128) { x += t; sc[tid] = x; }
        __syncthreads();
    }
    if (tid < 128) {
        int excl = x - myc;
        int node = b * 128 + tid;
        if (node < N_NODES) row_off[node] = e0 + excl;
        cursor[tid] = e0 + excl;
    }
    if (b == 0 && tid == 0) row_off[N_NODES] = N_EDGES;
    __syncthreads();
    for (int k = tid; k < ne; k += 256) {
        long long rec = part[e0 + k];
        int lo = (int)rec;
        int d7 = (lo >> 17) & 127;
        float w = __uint_as_float((unsigned)(rec >> 32));
        int pos = atomicAdd(&cursor[d7], 1);
        esec[pos] = make_int2((lo & 0x1FFFF) << 7, __float_as_int(w * sdinv[d7]));  // byte off: src*128 (bf16 row)
    }
}

// multiply in dinv[src]; zero 16 sentinel entries past N_EDGES (k_agg may overrun-read)
__global__ void k_coef(int2* __restrict__ esec, const float* __restrict__ dinv_g) {
    int e = blockIdx.x * 256 + threadIdx.x;
    if (e < N_EDGES) {
        int2 v = esec[e];
        esec[e] = make_int2(v.x, __float_as_int(__int_as_float(v.y) * dinv_g[((unsigned)v.x) >> 7]));
    } else if (e < N_EDGES + 16) {
        esec[e] = make_int2(0, 0);
    }
}

__global__ void k_gstart(const int* __restrict__ batch, int* gstart) {
    int g = blockIdx.x * 256 + threadIdx.x;
    if (g > N_GRAPHS) return;
    int lo = 0, hi = N_NODES;
    while (lo < hi) {
        int mid = (lo + hi) >> 1;
        if (batch[mid] < g) lo = mid + 1; else hi = mid;
    }
    gstart[g] = lo;
}

// ---------------- GEMM: H[N][64] = X[N][K] @ W[K][64], bf16 output ----------------
template <int K>
__global__ __launch_bounds__(256) void k_gemm(const float* __restrict__ X,
                                              const float* __restrict__ W,
                                              __hip_bfloat16* __restrict__ H) {
    constexpr int KC = 32;
    constexpr int XP = KC + 4;
    __shared__ float Xs[128 * XP];
    __shared__ float Ws[KC * F];
    const int tid  = threadIdx.x;
    const int fgrp = tid & 15;
    const int ngrp = tid >> 4;
    const int f0   = fgrp * 4;
    const int nb   = blockIdx.x * 128;

    float acc[8][4];
#pragma unroll
    for (int i = 0; i < 8; i++)
#pragma unroll
        for (int j = 0; j < 4; j++) acc[i][j] = 0.0f;

    for (int kc = 0; kc < K; kc += KC) {
        if (kc) __syncthreads();
#pragma unroll
        for (int pass = 0; pass < 4; pass++) {
            int idx = tid + pass * 256;
            int r = idx >> 3, q = idx & 7;
            int gr = nb + r; if (gr >= N_NODES) gr = N_NODES - 1;
            float4 v = *(const float4*)&X[(size_t)gr * K + kc + q * 4];
            *(float4*)&Xs[r * XP + q * 4] = v;
        }
#pragma unroll
        for (int pass = 0; pass < 2; pass++) {
            int idx = tid + pass * 256;
            float4 v = *(const float4*)&W[(size_t)(kc + (idx >> 4)) * F + (idx & 15) * 4];
            *(float4*)&Ws[idx * 4] = v;
        }
        __syncthreads();
#pragma unroll
        for (int k = 0; k < KC; k += 4) {
            float4 wv[4];
#pragma unroll
            for (int kk = 0; kk < 4; kk++)
                wv[kk] = *(const float4*)&Ws[(k + kk) * F + f0];
#pragma unroll
            for (int i = 0; i < 8; i++) {
                float4 xv = *(const float4*)&Xs[(ngrp + 16 * i) * XP + k];
                acc[i][0] = fmaf(xv.x, wv[0].x, acc[i][0]);
                acc[i][0] = fmaf(xv.y, wv[1].x, acc[i][0]);
                acc[i][0] = fmaf(xv.z, wv[2].x, acc[i][0]);
                acc[i][0] = fmaf(xv.w, wv[3].x, acc[i][0]);
                acc[i][1] = fmaf(xv.x, wv[0].y, acc[i][1]);
                acc[i][1] = fmaf(xv.y, wv[1].y, acc[i][1]);
                acc[i][1] = fmaf(xv.z, wv[2].y, acc[i][1]);
                acc[i][1] = fmaf(xv.w, wv[3].y, acc[i][1]);
                acc[i][2] = fmaf(xv.x, wv[0].z, acc[i][2]);
                acc[i][2] = fmaf(xv.y, wv[1].z, acc[i][2]);
                acc[i][2] = fmaf(xv.z, wv[2].z, acc[i][2]);
                acc[i][2] = fmaf(xv.w, wv[3].z, acc[i][2]);
                acc[i][3] = fmaf(xv.x, wv[0].w, acc[i][3]);
                acc[i][3] = fmaf(xv.y, wv[1].w, acc[i][3]);
                acc[i][3] = fmaf(xv.z, wv[2].w, acc[i][3]);
                acc[i][3] = fmaf(xv.w, wv[3].w, acc[i][3]);
            }
        }
    }
#pragma unroll
    for (int i = 0; i < 8; i++) {
        int gn = nb + ngrp + 16 * i;
        if (gn < N_NODES) {
            __hip_bfloat16 hb[4];
            hb[0] = __float2bfloat16(acc[i][0]);
            hb[1] = __float2bfloat16(acc[i][1]);
            hb[2] = __float2bfloat16(acc[i][2]);
            hb[3] = __float2bfloat16(acc[i][3]);
            *(uint2*)&H[(size_t)gn * F + f0] = *(uint2*)hb;
        }
    }
}

// ---------------- aggregation: O = relu(b + dinv^2*H + sum_in c*H[src]) ----------------
// one wave per node, lane = feature. 16-wide branch-free windows; overrun reads land
// in the next node's valid entries (or zeroed sentinels) and are killed by the
// wave-uniform coefficient select. esec.x is a pre-scaled byte offset (src*128, bf16 row).
__global__ __launch_bounds__(256) void k_agg(const __hip_bfloat16* __restrict__ H,
                                             const int* __restrict__ row_off,
                                             const long long* __restrict__ esec,
                                             const float* __restrict__ dinv,
                                             const float* __restrict__ bias,
                                             float* __restrict__ O) {
    int node = blockIdx.x * 4 + (threadIdx.x >> 6);
    int lane = threadIdx.x & 63;
    int beg = __builtin_amdgcn_readfirstlane(row_off[node]);
    int end = __builtin_amdgcn_readfirstlane(row_off[node + 1]);
    float di = dinv[node];
    const char* Hb = (const char*)H + lane * 2;
    float hself = __bfloat162float(H[(size_t)node * F + lane]);
    float base = bias[lane] + di * di * hself;
    float a[16];
#pragma unroll
    for (int u = 0; u < 16; u++) a[u] = 0.0f;
    for (int j = beg; j < end; j += 16) {
        long long e[16];
#pragma unroll
        for (int u = 0; u < 16; u++) e[u] = esec[j + u];   // wave-uniform -> scalar loads
#pragma unroll
        for (int u = 0; u < 16; u++) {
            unsigned off = (unsigned)(int)e[u];
            float c = (j + u < end) ? __int_as_float((int)(e[u] >> 32)) : 0.0f;  // uniform cond
            float hv = __bfloat162float(*(const __hip_bfloat16*)(Hb + off));
            a[u] = fmaf(c, hv, a[u]);
        }
    }
    float s0 = ((a[0] + a[1]) + (a[2] + a[3])) + ((a[4] + a[5]) + (a[6] + a[7]));
    float s1 = ((a[8] + a[9]) + (a[10] + a[11])) + ((a[12] + a[13]) + (a[14] + a[15]));
    O[(size_t)node * F + lane] = fmaxf(base + s0 + s1, 0.0f);
}

// ---------------- fused mean-pool + final linear ----------------
__global__ __launch_bounds__(256) void k_pool_linear(const float* __restrict__ H,
                                                     const int* __restrict__ gstart,
                                                     const float* __restrict__ Wl,
                                                     const float* __restrict__ bl,
                                                     float* __restrict__ out) {
    int g = blockIdx.x;
    int beg = gstart[g], end = gstart[g + 1];
    int lane = threadIdx.x & 63, wv = threadIdx.x >> 6;
    float acc = 0.0f;
    for (int r = beg + wv; r < end; r += 4)
        acc += H[(size_t)r * F + lane];
    __shared__ float s[4][F];
    s[wv][lane] = acc;
    __syncthreads();
    if (wv == 0) {
        float tot = s[0][lane] + s[1][lane] + s[2][lane] + s[3][lane];
        float cntf = (float)(end - beg);
        float p = tot / fmaxf(cntf, 1.0f);
        for (int c = 0; c < 10; c++) {
            float v = p * Wl[lane * 10 + c];
            for (int off = 32; off; off >>= 1) v += __shfl_down(v, off);
            if (lane == 0) out[g * 10 + c] = v + bl[c];
        }
    }
}

// ---------------- launch ----------------

extern "C" void kernel_launch(void* const* d_in, const int* in_sizes, int n_in,
                              void* d_out, int out_size, void* d_ws, size_t ws_size,
                              hipStream_t stream) {
    const float* x    = (const float*)d_in[0];
    const int*   ei   = (const int*)d_in[1];
    const float* ea   = (const float*)d_in[2];
    const int*   bat  = (const int*)d_in[3];
    const float* W1   = (const float*)d_in[4];
    const float* b1   = (const float*)d_in[5];
    const float* W2   = (const float*)d_in[6];
    const float* b2   = (const float*)d_in[7];
    const float* W3   = (const float*)d_in[8];
    const float* b3   = (const float*)d_in[9];
    const float* Wl   = (const float*)d_in[10];
    const float* bl   = (const float*)d_in[11];
    float* out = (float*)d_out;

    const int* src = ei;
    const int* dst = ei + N_EDGES;

    char* ws = (char*)d_ws;
    size_t off = 0;
    auto carve = [&](size_t bytes) {
        void* p = ws + off;
        off += (bytes + 255) & ~(size_t)255;
        return p;
    };
    float*          dinv    = (float*)carve(N_NODES * 4);
    int*            row_off = (int*)  carve((N_NODES + 1) * 4);
    int2*           esec    = (int2*) carve(((size_t)N_EDGES + 16) * 8);
    __hip_bfloat16* hbuf    = (__hip_bfloat16*)carve((size_t)N_NODES * F * 2);  // 12.8 MB
    float*          obuf    = (float*)carve((size_t)N_NODES * F * 4);           // 25.6 MB
    int*            gstart  = (int*)  carve((N_GRAPHS + 1) * 4);
    (void)ws_size; (void)in_sizes; (void)n_in; (void)out_size;

    // build-phase scratch: part aliases hbuf (exactly 12.8 MB), hist/btot/base alias obuf
    long long* part = (long long*)hbuf;
    char* alias = (char*)obuf;
    int* hist = (int*)alias;                         alias += (size_t)NCHUNK * NBUCK * 4;  // 2.45 MB
    int* btot = (int*)alias;                         alias += (NBUCK + 8) * 4;
    int* base = (int*)alias;

    const int EB  = (N_EDGES + 255) / 256 + 1;   // +1 block for the 16 sentinels
    const int GB  = (N_NODES + 127) / 128;       // 782

    k_hist     <<<NCHUNK, 256, 0, stream>>>(dst, hist);
    k_colscan  <<<NBUCK,  256, 0, stream>>>(hist, btot);
    k_bscan    <<<1,      256, 0, stream>>>(btot, base);
    k_partition<<<NCHUNK, 256, 0, stream>>>(src, dst, ea, hist, base, part);
    k_bucket   <<<NBUCK,  256, 0, stream>>>(part, base, dinv, row_off, esec);
    k_coef     <<<EB,     256, 0, stream>>>(esec, dinv);
    k_gstart   <<<2,      256, 0, stream>>>(bat, gstart);

    k_gemm<128><<<GB, 256, 0, stream>>>(x, W1, hbuf);
    k_agg<<<N_NODES / 4, 256, 0, stream>>>(hbuf, row_off, (const long long*)esec, dinv, b1, obuf);
    k_gemm<64><<<GB, 256, 0, stream>>>(obuf, W2, hbuf);
    k_agg<<<N_NODES / 4, 256, 0, stream>>>(hbuf, row_off, (const long long*)esec, dinv, b2, obuf);
    k_gemm<64><<<GB, 256, 0, stream>>>(obuf, W3, hbuf);
    k_agg<<<N_NODES / 4, 256, 0, stream>>>(hbuf, row_off, (const long long*)esec, dinv, b3, obuf);

    k_pool_linear<<<N_GRAPHS, 256, 0, stream>>>(obuf, gstart, Wl, bl, out);
}

// Round 6
// 418.785 us; speedup vs baseline: 2.1901x; 1.0063x over previous
//
#include <hip/hip_runtime.h>
#include <hip/hip_bf16.h>

#define N_NODES  100000
#define N_EDGES  1600000
#define N_GRAPHS 256
#define F 64
#define NBUCK  782   // ceil(N_NODES/128), bucket = dst >> 7
#define NCHUNK 782   // ceil(N_EDGES/2048), chunk = 2048 edges

// ======== atomic-free CSR build: two-level counting sort (proven) ========

__global__ __launch_bounds__(256) void k_hist(const int* __restrict__ dst, int* __restrict__ hist) {
    __shared__ int lh[NBUCK];
    int tid = threadIdx.x, chunk = blockIdx.x;
    for (int j = tid; j < NBUCK; j += 256) lh[j] = 0;
    __syncthreads();
    int e0 = chunk * 2048;
#pragma unroll
    for (int i = 0; i < 8; i++) {
        int e = e0 + i * 256 + tid;
        if (e < N_EDGES) atomicAdd(&lh[dst[e] >> 7], 1);
    }
    __syncthreads();
    for (int j = tid; j < NBUCK; j += 256) hist[chunk * NBUCK + j] = lh[j];
}

__global__ __launch_bounds__(256) void k_colscan(int* __restrict__ hist, int* __restrict__ btot) {
    __shared__ int ts[256];
    int b = blockIdx.x, tid = threadIdx.x;
    int v[4], loc[4], run = 0;
#pragma unroll
    for (int k = 0; k < 4; k++) {
        int c = tid * 4 + k;
        v[k] = (c < NCHUNK) ? hist[c * NBUCK + b] : 0;
        loc[k] = run; run += v[k];
    }
    ts[tid] = run;
    __syncthreads();
    int x = run;
    for (int off = 1; off < 256; off <<= 1) {
        int t = (tid >= off) ? ts[tid - off] : 0;
        __syncthreads();
        x += t; ts[tid] = x;
        __syncthreads();
    }
    int texcl = x - run;
#pragma unroll
    for (int k = 0; k < 4; k++) {
        int c = tid * 4 + k;
        if (c < NCHUNK) hist[c * NBUCK + b] = texcl + loc[k];
    }
    if (tid == 255) btot[b] = x;
}

__global__ __launch_bounds__(256) void k_bscan(const int* __restrict__ btot, int* __restrict__ base) {
    __shared__ int ts[256];
    int tid = threadIdx.x;
    int v[4], loc[4], run = 0;
#pragma unroll
    for (int k = 0; k < 4; k++) {
        int c = tid * 4 + k;
        v[k] = (c < NBUCK) ? btot[c] : 0;
        loc[k] = run; run += v[k];
    }
    ts[tid] = run;
    __syncthreads();
    int x = run;
    for (int off = 1; off < 256; off <<= 1) {
        int t = (tid >= off) ? ts[tid - off] : 0;
        __syncthreads();
        x += t; ts[tid] = x;
        __syncthreads();
    }
    int texcl = x - run;
#pragma unroll
    for (int k = 0; k < 4; k++) {
        int c = tid * 4 + k;
        if (c < NBUCK) base[c] = texcl + loc[k];
    }
    if (tid == 255) base[NBUCK] = x;
}

__global__ __launch_bounds__(256) void k_partition(const int* __restrict__ src, const int* __restrict__ dst,
                                                   const float* __restrict__ ew,
                                                   const int* __restrict__ hist, const int* __restrict__ base,
                                                   long long* __restrict__ part) {
    __shared__ int cursor[NBUCK];
    int tid = threadIdx.x, chunk = blockIdx.x;
    for (int j = tid; j < NBUCK; j += 256) cursor[j] = base[j] + hist[chunk * NBUCK + j];
    __syncthreads();
    int e0 = chunk * 2048;
#pragma unroll
    for (int i = 0; i < 8; i++) {
        int e = e0 + i * 256 + tid;
        if (e < N_EDGES) {
            int d = dst[e];
            int pos = atomicAdd(&cursor[d >> 7], 1);
            unsigned lo = (unsigned)src[e] | ((unsigned)(d & 127) << 17);
            long long rec = (long long)((unsigned long long)lo |
                            ((unsigned long long)__float_as_uint(ew[e]) << 32));
            part[pos] = rec;
        }
    }
}

// per-bucket: deg (LDS atomics) -> dinv, cnt -> row_off, scatter esec=(src*128, ew*dinv[d])
__global__ __launch_bounds__(256) void k_bucket(const long long* __restrict__ part,
                                                const int* __restrict__ base,
                                                float* __restrict__ dinv_g, int* __restrict__ row_off,
                                                int2* __restrict__ esec) {
    __shared__ float fdeg[128];
    __shared__ float sdinv[128];
    __shared__ int   cnt[128];
    __shared__ int   sc[128];
    __shared__ int   cursor[128];
    int b = blockIdx.x, tid = threadIdx.x;
    if (tid < 128) { fdeg[tid] = 1.0f; cnt[tid] = 0; }   // 1.0 = self-loop weight
    __syncthreads();
    int e0 = base[b], e1 = base[b + 1], ne = e1 - e0;
    for (int k = tid; k < ne; k += 256) {
        long long rec = part[e0 + k];
        int lo = (int)rec;
        int d7 = (lo >> 17) & 127;
        atomicAdd(&fdeg[d7], __uint_as_float((unsigned)(rec >> 32)));
        atomicAdd(&cnt[d7], 1);
    }
    __syncthreads();
    int myc = 0, x = 0;
    if (tid < 128) {
        float dv = rsqrtf(fdeg[tid]);
        sdinv[tid] = dv;
        int node = b * 128 + tid;
        if (node < N_NODES) dinv_g[node] = dv;
        myc = cnt[tid]; x = myc; sc[tid] = x;
    }
    __syncthreads();
    for (int off = 1; off < 128; off <<= 1) {
        int t = (tid < 128 && tid >= off) ? sc[tid - off] : 0;
        __syncthreads();
        if (tid < 128) { x += t; sc[tid] = x; }
        __syncthreads();
    }
    if (tid < 128) {
        int excl = x - myc;
        int node = b * 128 + tid;
        if (node < N_NODES) row_off[node] = e0 + excl;
        cursor[tid] = e0 + excl;
    }
    if (b == 0 && tid == 0) row_off[N_NODES] = N_EDGES;
    __syncthreads();
    for (int k = tid; k < ne; k += 256) {
        long long rec = part[e0 + k];
        int lo = (int)rec;
        int d7 = (lo >> 17) & 127;
        float w = __uint_as_float((unsigned)(rec >> 32));
        int pos = atomicAdd(&cursor[d7], 1);
        esec[pos] = make_int2((lo & 0x1FFFF) << 7, __float_as_int(w * sdinv[d7]));  // byte off: src*128 (bf16 row)
    }
}

// multiply in dinv[src]; zero 16 sentinel entries past N_EDGES (k_agg overrun-reads)
__global__ void k_coef(int2* __restrict__ esec, const float* __restrict__ dinv_g) {
    int e = blockIdx.x * 256 + threadIdx.x;
    if (e < N_EDGES) {
        int2 v = esec[e];
        esec[e] = make_int2(v.x, __float_as_int(__int_as_float(v.y) * dinv_g[((unsigned)v.x) >> 7]));
    } else if (e < N_EDGES + 16) {
        esec[e] = make_int2(0, 0);
    }
}

__global__ void k_gstart(const int* __restrict__ batch, int* gstart) {
    int g = blockIdx.x * 256 + threadIdx.x;
    if (g > N_GRAPHS) return;
    int lo = 0, hi = N_NODES;
    while (lo < hi) {
        int mid = (lo + hi) >> 1;
        if (batch[mid] < g) lo = mid + 1; else hi = mid;
    }
    gstart[g] = lo;
}

// ---------------- GEMM: H[N][64] = X[N][K] @ W[K][64], bf16 output ----------------
// BF16IN: X is bf16 (unpacked to fp32 during LDS staging — numerically exact).
template <int K, bool BF16IN>
__global__ __launch_bounds__(256) void k_gemm(const void* __restrict__ Xv,
                                              const float* __restrict__ W,
                                              __hip_bfloat16* __restrict__ H) {
    constexpr int KC = 32;
    constexpr int XP = KC + 4;
    __shared__ float Xs[128 * XP];
    __shared__ float Ws[KC * F];
    const int tid  = threadIdx.x;
    const int fgrp = tid & 15;
    const int ngrp = tid >> 4;
    const int f0   = fgrp * 4;
    const int nb   = blockIdx.x * 128;

    float acc[8][4];
#pragma unroll
    for (int i = 0; i < 8; i++)
#pragma unroll
        for (int j = 0; j < 4; j++) acc[i][j] = 0.0f;

    for (int kc = 0; kc < K; kc += KC) {
        if (kc) __syncthreads();
        if (BF16IN) {
            const unsigned short* X = (const unsigned short*)Xv;
            // 128 rows x 32 cols, 8 bf16 per load -> 512 loads, 2 passes
#pragma unroll
            for (int pass = 0; pass < 2; pass++) {
                int idx = tid + pass * 256;
                int r = idx >> 2, q = idx & 3;
                int gr = nb + r; if (gr >= N_NODES) gr = N_NODES - 1;
                uint4 v = *(const uint4*)&X[(size_t)gr * K + kc + q * 8];
                float* dp = &Xs[r * XP + q * 8];
                dp[0] = __uint_as_float(v.x << 16);
                dp[1] = __uint_as_float(v.x & 0xffff0000u);
                dp[2] = __uint_as_float(v.y << 16);
                dp[3] = __uint_as_float(v.y & 0xffff0000u);
                dp[4] = __uint_as_float(v.z << 16);
                dp[5] = __uint_as_float(v.z & 0xffff0000u);
                dp[6] = __uint_as_float(v.w << 16);
                dp[7] = __uint_as_float(v.w & 0xffff0000u);
            }
        } else {
            const float* X = (const float*)Xv;
#pragma unroll
            for (int pass = 0; pass < 4; pass++) {
                int idx = tid + pass * 256;
                int r = idx >> 3, q = idx & 7;
                int gr = nb + r; if (gr >= N_NODES) gr = N_NODES - 1;
                float4 v = *(const float4*)&X[(size_t)gr * K + kc + q * 4];
                *(float4*)&Xs[r * XP + q * 4] = v;
            }
        }
#pragma unroll
        for (int pass = 0; pass < 2; pass++) {
            int idx = tid + pass * 256;
            float4 v = *(const float4*)&W[(size_t)(kc + (idx >> 4)) * F + (idx & 15) * 4];
            *(float4*)&Ws[idx * 4] = v;
        }
        __syncthreads();
#pragma unroll
        for (int k = 0; k < KC; k += 4) {
            float4 wv[4];
#pragma unroll
            for (int kk = 0; kk < 4; kk++)
                wv[kk] = *(const float4*)&Ws[(k + kk) * F + f0];
#pragma unroll
            for (int i = 0; i < 8; i++) {
                float4 xv = *(const float4*)&Xs[(ngrp + 16 * i) * XP + k];
                acc[i][0] = fmaf(xv.x, wv[0].x, acc[i][0]);
                acc[i][0] = fmaf(xv.y, wv[1].x, acc[i][0]);
                acc[i][0] = fmaf(xv.z, wv[2].x, acc[i][0]);
                acc[i][0] = fmaf(xv.w, wv[3].x, acc[i][0]);
                acc[i][1] = fmaf(xv.x, wv[0].y, acc[i][1]);
                acc[i][1] = fmaf(xv.y, wv[1].y, acc[i][1]);
                acc[i][1] = fmaf(xv.z, wv[2].y, acc[i][1]);
                acc[i][1] = fmaf(xv.w, wv[3].y, acc[i][1]);
                acc[i][2] = fmaf(xv.x, wv[0].z, acc[i][2]);
                acc[i][2] = fmaf(xv.y, wv[1].z, acc[i][2]);
                acc[i][2] = fmaf(xv.z, wv[2].z, acc[i][2]);
                acc[i][2] = fmaf(xv.w, wv[3].z, acc[i][2]);
                acc[i][3] = fmaf(xv.x, wv[0].w, acc[i][3]);
                acc[i][3] = fmaf(xv.y, wv[1].w, acc[i][3]);
                acc[i][3] = fmaf(xv.z, wv[2].w, acc[i][3]);
                acc[i][3] = fmaf(xv.w, wv[3].w, acc[i][3]);
            }
        }
    }
#pragma unroll
    for (int i = 0; i < 8; i++) {
        int gn = nb + ngrp + 16 * i;
        if (gn < N_NODES) {
            __hip_bfloat16 hb[4];
            hb[0] = __float2bfloat16(acc[i][0]);
            hb[1] = __float2bfloat16(acc[i][1]);
            hb[2] = __float2bfloat16(acc[i][2]);
            hb[3] = __float2bfloat16(acc[i][3]);
            *(uint2*)&H[(size_t)gn * F + f0] = *(uint2*)hb;
        }
    }
}

// ---------------- aggregation: O = relu(b + dinv^2*H + sum_in c*H[src]) ----------------
// One wave per node. Lane = (q = l>>3 edge slot, f8 = l&7 feature group).
// Each lane gathers dwordx4 = 8 bf16 feats -> one wave instruction covers 8 edges (1KB).
// Per 8-lane group reads its own esec entry (broadcast load; coefficient in VGPR).
// Tail: c forced 0 for j+q >= end (overrun reads hit next node's entries / sentinels).
// Epilogue: shfl_xor reduction over q, lanes q==0 write the bf16 row.
__global__ __launch_bounds__(256) void k_agg(const __hip_bfloat16* __restrict__ H,
                                             const int* __restrict__ row_off,
                                             const int2* __restrict__ esec,
                                             const float* __restrict__ dinv,
                                             const float* __restrict__ bias,
                                             __hip_bfloat16* __restrict__ O) {
    int node = blockIdx.x * 4 + (threadIdx.x >> 6);
    int lane = threadIdx.x & 63;
    int q  = lane >> 3;
    int f8 = lane & 7;
    int beg = __builtin_amdgcn_readfirstlane(row_off[node]);
    int end = __builtin_amdgcn_readfirstlane(row_off[node + 1]);
    const char* Hbase = (const char*)H;

    float a[8];
#pragma unroll
    for (int u = 0; u < 8; u++) a[u] = 0.0f;

    for (int j = beg; j < end; j += 8) {
        int2 ev = esec[j + q];                       // 8-lane broadcast
        float c = (j + q < end) ? __int_as_float(ev.y) : 0.0f;
        uint4 hq = *(const uint4*)(Hbase + (unsigned)ev.x + (f8 << 4));
        a[0] = fmaf(c, __uint_as_float(hq.x << 16),         a[0]);
        a[1] = fmaf(c, __uint_as_float(hq.x & 0xffff0000u), a[1]);
        a[2] = fmaf(c, __uint_as_float(hq.y << 16),         a[2]);
        a[3] = fmaf(c, __uint_as_float(hq.y & 0xffff0000u), a[3]);
        a[4] = fmaf(c, __uint_as_float(hq.z << 16),         a[4]);
        a[5] = fmaf(c, __uint_as_float(hq.z & 0xffff0000u), a[5]);
        a[6] = fmaf(c, __uint_as_float(hq.w << 16),         a[6]);
        a[7] = fmaf(c, __uint_as_float(hq.w & 0xffff0000u), a[7]);
    }
    // reduce over the 8 edge slots (q): xor 8,16,32
#pragma unroll
    for (int m = 8; m < 64; m <<= 1) {
#pragma unroll
        for (int u = 0; u < 8; u++) a[u] += __shfl_xor(a[u], m);
    }
    if (q == 0) {
        float di = dinv[node];
        float di2 = di * di;
        uint4 hs = *(const uint4*)(Hbase + (size_t)node * 128 + (f8 << 4));
        float hv[8];
        hv[0] = __uint_as_float(hs.x << 16);
        hv[1] = __uint_as_float(hs.x & 0xffff0000u);
        hv[2] = __uint_as_float(hs.y << 16);
        hv[3] = __uint_as_float(hs.y & 0xffff0000u);
        hv[4] = __uint_as_float(hs.z << 16);
        hv[5] = __uint_as_float(hs.z & 0xffff0000u);
        hv[6] = __uint_as_float(hs.w << 16);
        hv[7] = __uint_as_float(hs.w & 0xffff0000u);
        const float4* bp = (const float4*)(bias + f8 * 8);
        float4 b0 = bp[0], b1 = bp[1];
        float r[8];
        r[0] = fmaxf(a[0] + b0.x + di2 * hv[0], 0.0f);
        r[1] = fmaxf(a[1] + b0.y + di2 * hv[1], 0.0f);
        r[2] = fmaxf(a[2] + b0.z + di2 * hv[2], 0.0f);
        r[3] = fmaxf(a[3] + b0.w + di2 * hv[3], 0.0f);
        r[4] = fmaxf(a[4] + b1.x + di2 * hv[4], 0.0f);
        r[5] = fmaxf(a[5] + b1.y + di2 * hv[5], 0.0f);
        r[6] = fmaxf(a[6] + b1.z + di2 * hv[6], 0.0f);
        r[7] = fmaxf(a[7] + b1.w + di2 * hv[7], 0.0f);
        __hip_bfloat16 hb[8];
#pragma unroll
        for (int u = 0; u < 8; u++) hb[u] = __float2bfloat16(r[u]);
        *(uint4*)&O[(size_t)node * F + f8 * 8] = *(uint4*)hb;
    }
}

// ---------------- fused mean-pool + final linear (bf16 input) ----------------
__global__ __launch_bounds__(256) void k_pool_linear(const __hip_bfloat16* __restrict__ H,
                                                     const int* __restrict__ gstart,
                                                     const float* __restrict__ Wl,
                                                     const float* __restrict__ bl,
                                                     float* __restrict__ out) {
    int g = blockIdx.x;
    int beg = gstart[g], end = gstart[g + 1];
    int lane = threadIdx.x & 63, wv = threadIdx.x >> 6;
    float acc = 0.0f;
    for (int r = beg + wv; r < end; r += 4)
        acc += __bfloat162float(H[(size_t)r * F + lane]);
    __shared__ float s[4][F];
    s[wv][lane] = acc;
    __syncthreads();
    if (wv == 0) {
        float tot = s[0][lane] + s[1][lane] + s[2][lane] + s[3][lane];
        float cntf = (float)(end - beg);
        float p = tot / fmaxf(cntf, 1.0f);
        for (int c = 0; c < 10; c++) {
            float v = p * Wl[lane * 10 + c];
            for (int off = 32; off; off >>= 1) v += __shfl_down(v, off);
            if (lane == 0) out[g * 10 + c] = v + bl[c];
        }
    }
}

// ---------------- launch ----------------

extern "C" void kernel_launch(void* const* d_in, const int* in_sizes, int n_in,
                              void* d_out, int out_size, void* d_ws, size_t ws_size,
                              hipStream_t stream) {
    const float* x    = (const float*)d_in[0];
    const int*   ei   = (const int*)d_in[1];
    const float* ea   = (const float*)d_in[2];
    const int*   bat  = (const int*)d_in[3];
    const float* W1   = (const float*)d_in[4];
    const float* b1   = (const float*)d_in[5];
    const float* W2   = (const float*)d_in[6];
    const float* b2   = (const float*)d_in[7];
    const float* W3   = (const float*)d_in[8];
    const float* b3   = (const float*)d_in[9];
    const float* Wl   = (const float*)d_in[10];
    const float* bl   = (const float*)d_in[11];
    float* out = (float*)d_out;

    const int* src = ei;
    const int* dst = ei + N_EDGES;

    char* ws = (char*)d_ws;
    size_t off = 0;
    auto carve = [&](size_t bytes) {
        void* p = ws + off;
        off += (bytes + 255) & ~(size_t)255;
        return p;
    };
    float*          dinv    = (float*)carve(N_NODES * 4);
    int*            row_off = (int*)  carve((N_NODES + 1) * 4);
    int2*           esec    = (int2*) carve(((size_t)N_EDGES + 16) * 8);
    __hip_bfloat16* hbuf    = (__hip_bfloat16*)carve((size_t)N_NODES * F * 2);  // 12.8 MB
    __hip_bfloat16* obuf    = (__hip_bfloat16*)carve((size_t)N_NODES * F * 4);  // carve 25.6 MB (aliased by build)
    int*            gstart  = (int*)  carve((N_GRAPHS + 1) * 4);
    (void)ws_size; (void)in_sizes; (void)n_in; (void)out_size;

    // build-phase scratch: part aliases hbuf (exactly 12.8 MB), hist/btot/base alias obuf tail
    long long* part = (long long*)hbuf;
    char* alias = (char*)obuf + (size_t)N_NODES * F * 2;   // past live bf16 obuf region
    int* hist = (int*)alias;                         alias += (size_t)NCHUNK * NBUCK * 4;  // 2.45 MB
    int* btot = (int*)alias;                         alias += (NBUCK + 8) * 4;
    int* base = (int*)alias;

    const int EB  = (N_EDGES + 255) / 256 + 1;   // +1 block for the 16 sentinels
    const int GB  = (N_NODES + 127) / 128;       // 782

    k_hist     <<<NCHUNK, 256, 0, stream>>>(dst, hist);
    k_colscan  <<<NBUCK,  256, 0, stream>>>(hist, btot);
    k_bscan    <<<1,      256, 0, stream>>>(btot, base);
    k_partition<<<NCHUNK, 256, 0, stream>>>(src, dst, ea, hist, base, part);
    k_bucket   <<<NBUCK,  256, 0, stream>>>(part, base, dinv, row_off, esec);
    k_coef     <<<EB,     256, 0, stream>>>(esec, dinv);
    k_gstart   <<<2,      256, 0, stream>>>(bat, gstart);

    k_gemm<128, false><<<GB, 256, 0, stream>>>(x, W1, hbuf);
    k_agg<<<N_NODES / 4, 256, 0, stream>>>(hbuf, row_off, esec, dinv, b1, obuf);
    k_gemm<64, true><<<GB, 256, 0, stream>>>(obuf, W2, hbuf);
    k_agg<<<N_NODES / 4, 256, 0, stream>>>(hbuf, row_off, esec, dinv, b2, obuf);
    k_gemm<64, true><<<GB, 256, 0, stream>>>(obuf, W3, hbuf);
    k_agg<<<N_NODES / 4, 256, 0, stream>>>(hbuf, row_off, esec, dinv, b3, obuf);

    k_pool_linear<<<N_GRAPHS, 256, 0, stream>>>(obuf, gstart, Wl, bl, out);
}

// Round 7
// 385.192 us; speedup vs baseline: 2.3810x; 1.0872x over previous
//
#include <hip/hip_runtime.h>
#include <hip/hip_bf16.h>

#define N_NODES  100000
#define N_EDGES  1600000
#define N_GRAPHS 256
#define F 64
#define NBUCK  782    // ceil(N_NODES/128), bucket = dst >> 7
#define CHUNK  8192   // edges per partition chunk
#define NCHUNK 196    // ceil(1.6M/8192)

// ======== atomic-free CSR build: two-level counting sort ========

__global__ __launch_bounds__(256) void k_hist(const int* __restrict__ dst, int* __restrict__ hist) {
    __shared__ int lh[NBUCK];
    int tid = threadIdx.x, chunk = blockIdx.x;
    for (int j = tid; j < NBUCK; j += 256) lh[j] = 0;
    __syncthreads();
    int e0 = chunk * CHUNK;
#pragma unroll
    for (int i = 0; i < CHUNK / 256; i++) {
        int e = e0 + i * 256 + tid;
        if (e < N_EDGES) atomicAdd(&lh[dst[e] >> 7], 1);
    }
    __syncthreads();
    for (int j = tid; j < NBUCK; j += 256) hist[chunk * NBUCK + j] = lh[j];
}

// per-bucket column scan over chunks (NCHUNK <= 256: one chunk per thread)
__global__ __launch_bounds__(256) void k_colscan(int* __restrict__ hist, int* __restrict__ btot) {
    __shared__ int ts[256];
    int b = blockIdx.x, tid = threadIdx.x;
    int v = (tid < NCHUNK) ? hist[tid * NBUCK + b] : 0;
    ts[tid] = v;
    __syncthreads();
    int x = v;
    for (int off = 1; off < 256; off <<= 1) {
        int t = (tid >= off) ? ts[tid - off] : 0;
        __syncthreads();
        x += t; ts[tid] = x;
        __syncthreads();
    }
    if (tid < NCHUNK) hist[tid * NBUCK + b] = x - v;
    if (tid == 255) btot[b] = x;
}

__global__ __launch_bounds__(256) void k_bscan(const int* __restrict__ btot, int* __restrict__ base) {
    __shared__ int ts[256];
    int tid = threadIdx.x;
    int v[4], loc[4], run = 0;
#pragma unroll
    for (int k = 0; k < 4; k++) {
        int c = tid * 4 + k;
        v[k] = (c < NBUCK) ? btot[c] : 0;
        loc[k] = run; run += v[k];
    }
    ts[tid] = run;
    __syncthreads();
    int x = run;
    for (int off = 1; off < 256; off <<= 1) {
        int t = (tid >= off) ? ts[tid - off] : 0;
        __syncthreads();
        x += t; ts[tid] = x;
        __syncthreads();
    }
    int texcl = x - run;
#pragma unroll
    for (int k = 0; k < 4; k++) {
        int c = tid * 4 + k;
        if (c < NBUCK) base[c] = texcl + loc[k];
    }
    if (tid == 255) base[NBUCK] = x;
}

__global__ __launch_bounds__(256) void k_partition(const int* __restrict__ src, const int* __restrict__ dst,
                                                   const float* __restrict__ ew,
                                                   const int* __restrict__ hist, const int* __restrict__ base,
                                                   long long* __restrict__ part) {
    __shared__ int cursor[NBUCK];
    int tid = threadIdx.x, chunk = blockIdx.x;
    for (int j = tid; j < NBUCK; j += 256) cursor[j] = base[j] + hist[chunk * NBUCK + j];
    __syncthreads();
    int e0 = chunk * CHUNK;
#pragma unroll
    for (int i = 0; i < CHUNK / 256; i++) {
        int e = e0 + i * 256 + tid;
        if (e < N_EDGES) {
            int d = dst[e];
            int pos = atomicAdd(&cursor[d >> 7], 1);
            unsigned lo = (unsigned)src[e] | ((unsigned)(d & 127) << 17);
            long long rec = (long long)((unsigned long long)lo |
                            ((unsigned long long)__float_as_uint(ew[e]) << 32));
            part[pos] = rec;
        }
    }
}

// per-bucket: deg (LDS atomics) -> dinv, cnt -> row_off, scatter esec=(src*128, ew*dinv[d])
__global__ __launch_bounds__(256) void k_bucket(const long long* __restrict__ part,
                                                const int* __restrict__ base,
                                                float* __restrict__ dinv_g, int* __restrict__ row_off,
                                                int2* __restrict__ esec) {
    __shared__ float fdeg[128];
    __shared__ float sdinv[128];
    __shared__ int   cnt[128];
    __shared__ int   sc[128];
    __shared__ int   cursor[128];
    int b = blockIdx.x, tid = threadIdx.x;
    if (tid < 128) { fdeg[tid] = 1.0f; cnt[tid] = 0; }   // 1.0 = self-loop weight
    __syncthreads();
    int e0 = base[b], e1 = base[b + 1], ne = e1 - e0;
    for (int k = tid; k < ne; k += 256) {
        long long rec = part[e0 + k];
        int lo = (int)rec;
        int d7 = (lo >> 17) & 127;
        atomicAdd(&fdeg[d7], __uint_as_float((unsigned)(rec >> 32)));
        atomicAdd(&cnt[d7], 1);
    }
    __syncthreads();
    int myc = 0, x = 0;
    if (tid < 128) {
        float dv = rsqrtf(fdeg[tid]);
        sdinv[tid] = dv;
        int node = b * 128 + tid;
        if (node < N_NODES) dinv_g[node] = dv;
        myc = cnt[tid]; x = myc; sc[tid] = x;
    }
    __syncthreads();
    for (int off = 1; off < 128; off <<= 1) {
        int t = (tid < 128 && tid >= off) ? sc[tid - off] : 0;
        __syncthreads();
        if (tid < 128) { x += t; sc[tid] = x; }
        __syncthreads();
    }
    if (tid < 128) {
        int excl = x - myc;
        int node = b * 128 + tid;
        if (node < N_NODES) row_off[node] = e0 + excl;
        cursor[tid] = e0 + excl;
    }
    if (b == 0 && tid == 0) row_off[N_NODES] = N_EDGES;
    __syncthreads();
    for (int k = tid; k < ne; k += 256) {
        long long rec = part[e0 + k];
        int lo = (int)rec;
        int d7 = (lo >> 17) & 127;
        float w = __uint_as_float((unsigned)(rec >> 32));
        int pos = atomicAdd(&cursor[d7], 1);
        esec[pos] = make_int2((lo & 0x1FFFF) << 7, __float_as_int(w * sdinv[d7]));  // byte off: src*128 (bf16 row)
    }
}

// multiply in dinv[src]; zero 16 sentinel entries past N_EDGES (k_agg overrun-reads)
__global__ void k_coef(int2* __restrict__ esec, const float* __restrict__ dinv_g) {
    int e = blockIdx.x * 256 + threadIdx.x;
    if (e < N_EDGES) {
        int2 v = esec[e];
        esec[e] = make_int2(v.x, __float_as_int(__int_as_float(v.y) * dinv_g[((unsigned)v.x) >> 7]));
    } else if (e < N_EDGES + 16) {
        esec[e] = make_int2(0, 0);
    }
}

__global__ void k_gstart(const int* __restrict__ batch, int* gstart) {
    int g = blockIdx.x * 256 + threadIdx.x;
    if (g > N_GRAPHS) return;
    int lo = 0, hi = N_NODES;
    while (lo < hi) {
        int mid = (lo + hi) >> 1;
        if (batch[mid] < g) lo = mid + 1; else hi = mid;
    }
    gstart[g] = lo;
}

// ---------------- GEMM: H[N][64] = X[N][K] @ W[K][64], bf16 output ----------------
template <int K, bool BF16IN>
__global__ __launch_bounds__(256) void k_gemm(const void* __restrict__ Xv,
                                              const float* __restrict__ W,
                                              __hip_bfloat16* __restrict__ H) {
    constexpr int KC = 32;
    constexpr int XP = KC + 4;
    __shared__ float Xs[128 * XP];
    __shared__ float Ws[KC * F];
    const int tid  = threadIdx.x;
    const int fgrp = tid & 15;
    const int ngrp = tid >> 4;
    const int f0   = fgrp * 4;
    const int nb   = blockIdx.x * 128;

    float acc[8][4];
#pragma unroll
    for (int i = 0; i < 8; i++)
#pragma unroll
        for (int j = 0; j < 4; j++) acc[i][j] = 0.0f;

    for (int kc = 0; kc < K; kc += KC) {
        if (kc) __syncthreads();
        if (BF16IN) {
            const unsigned short* X = (const unsigned short*)Xv;
#pragma unroll
            for (int pass = 0; pass < 2; pass++) {
                int idx = tid + pass * 256;
                int r = idx >> 2, q = idx & 3;
                int gr = nb + r; if (gr >= N_NODES) gr = N_NODES - 1;
                uint4 v = *(const uint4*)&X[(size_t)gr * K + kc + q * 8];
                float* dp = &Xs[r * XP + q * 8];
                dp[0] = __uint_as_float(v.x << 16);
                dp[1] = __uint_as_float(v.x & 0xffff0000u);
                dp[2] = __uint_as_float(v.y << 16);
                dp[3] = __uint_as_float(v.y & 0xffff0000u);
                dp[4] = __uint_as_float(v.z << 16);
                dp[5] = __uint_as_float(v.z & 0xffff0000u);
                dp[6] = __uint_as_float(v.w << 16);
                dp[7] = __uint_as_float(v.w & 0xffff0000u);
            }
        } else {
            const float* X = (const float*)Xv;
#pragma unroll
            for (int pass = 0; pass < 4; pass++) {
                int idx = tid + pass * 256;
                int r = idx >> 3, q = idx & 7;
                int gr = nb + r; if (gr >= N_NODES) gr = N_NODES - 1;
                float4 v = *(const float4*)&X[(size_t)gr * K + kc + q * 4];
                *(float4*)&Xs[r * XP + q * 4] = v;
            }
        }
#pragma unroll
        for (int pass = 0; pass < 2; pass++) {
            int idx = tid + pass * 256;
            float4 v = *(const float4*)&W[(size_t)(kc + (idx >> 4)) * F + (idx & 15) * 4];
            *(float4*)&Ws[idx * 4] = v;
        }
        __syncthreads();
#pragma unroll
        for (int k = 0; k < KC; k += 4) {
            float4 wv[4];
#pragma unroll
            for (int kk = 0; kk < 4; kk++)
                wv[kk] = *(const float4*)&Ws[(k + kk) * F + f0];
#pragma unroll
            for (int i = 0; i < 8; i++) {
                float4 xv = *(const float4*)&Xs[(ngrp + 16 * i) * XP + k];
                acc[i][0] = fmaf(xv.x, wv[0].x, acc[i][0]);
                acc[i][0] = fmaf(xv.y, wv[1].x, acc[i][0]);
                acc[i][0] = fmaf(xv.z, wv[2].x, acc[i][0]);
                acc[i][0] = fmaf(xv.w, wv[3].x, acc[i][0]);
                acc[i][1] = fmaf(xv.x, wv[0].y, acc[i][1]);
                acc[i][1] = fmaf(xv.y, wv[1].y, acc[i][1]);
                acc[i][1] = fmaf(xv.z, wv[2].y, acc[i][1]);
                acc[i][1] = fmaf(xv.w, wv[3].y, acc[i][1]);
                acc[i][2] = fmaf(xv.x, wv[0].z, acc[i][2]);
                acc[i][2] = fmaf(xv.y, wv[1].z, acc[i][2]);
                acc[i][2] = fmaf(xv.z, wv[2].z, acc[i][2]);
                acc[i][2] = fmaf(xv.w, wv[3].z, acc[i][2]);
                acc[i][3] = fmaf(xv.x, wv[0].w, acc[i][3]);
                acc[i][3] = fmaf(xv.y, wv[1].w, acc[i][3]);
                acc[i][3] = fmaf(xv.z, wv[2].w, acc[i][3]);
                acc[i][3] = fmaf(xv.w, wv[3].w, acc[i][3]);
            }
        }
    }
#pragma unroll
    for (int i = 0; i < 8; i++) {
        int gn = nb + ngrp + 16 * i;
        if (gn < N_NODES) {
            __hip_bfloat16 hb[4];
            hb[0] = __float2bfloat16(acc[i][0]);
            hb[1] = __float2bfloat16(acc[i][1]);
            hb[2] = __float2bfloat16(acc[i][2]);
            hb[3] = __float2bfloat16(acc[i][3]);
            *(uint2*)&H[(size_t)gn * F + f0] = *(uint2*)hb;
        }
    }
}

// ---------------- aggregation: O = relu(b + dinv^2*H + sum_in c*H[src]) ----------------
// TWO nodes per wave (independent gather chains -> 16 cache lines in flight,
// fixed overhead amortized). Lane = (q = l>>3 edge slot, f8 = l&7 feat group);
// each lane gathers dwordx4 = 8 bf16 feats; per 8-lane group reads its own esec
// entry. Tail: index clamp to zeroed sentinels + per-node coefficient kill.
// Epilogue: shfl_xor reduce over q; lane groups q==0 / q==1 write node0 / node1.
__global__ __launch_bounds__(256) void k_agg(const __hip_bfloat16* __restrict__ H,
                                             const int* __restrict__ row_off,
                                             const int2* __restrict__ esec,
                                             const float* __restrict__ dinv,
                                             const float* __restrict__ bias,
                                             __hip_bfloat16* __restrict__ O) {
    int wv   = threadIdx.x >> 6;
    int lane = threadIdx.x & 63;
    int np   = blockIdx.x * 8 + wv * 2;          // first node of the pair
    int q  = lane >> 3;
    int f8 = lane & 7;
    int b0 = __builtin_amdgcn_readfirstlane(row_off[np]);
    int m0 = __builtin_amdgcn_readfirstlane(row_off[np + 1]);
    int e1 = __builtin_amdgcn_readfirstlane(row_off[np + 2]);
    const char* Hbase = (const char*)H;

    float a0[8], a1[8];
#pragma unroll
    for (int u = 0; u < 8; u++) { a0[u] = 0.0f; a1[u] = 0.0f; }

    int len0 = m0 - b0, len1 = e1 - m0;
    int maxlen = len0 > len1 ? len0 : len1;
    int iters = (maxlen + 7) >> 3;
    int j0 = b0 + q, j1 = m0 + q;
    for (int it = 0; it < iters; it++, j0 += 8, j1 += 8) {
        int i0 = j0 < N_EDGES ? j0 : N_EDGES;    // clamp into zeroed sentinels
        int i1 = j1 < N_EDGES ? j1 : N_EDGES;
        int2 ev0 = esec[i0];
        int2 ev1 = esec[i1];
        float c0 = (j0 < m0) ? __int_as_float(ev0.y) : 0.0f;
        float c1 = (j1 < e1) ? __int_as_float(ev1.y) : 0.0f;
        uint4 h0 = *(const uint4*)(Hbase + (unsigned)ev0.x + (f8 << 4));
        uint4 h1 = *(const uint4*)(Hbase + (unsigned)ev1.x + (f8 << 4));
        a0[0] = fmaf(c0, __uint_as_float(h0.x << 16),         a0[0]);
        a0[1] = fmaf(c0, __uint_as_float(h0.x & 0xffff0000u), a0[1]);
        a0[2] = fmaf(c0, __uint_as_float(h0.y << 16),         a0[2]);
        a0[3] = fmaf(c0, __uint_as_float(h0.y & 0xffff0000u), a0[3]);
        a0[4] = fmaf(c0, __uint_as_float(h0.z << 16),         a0[4]);
        a0[5] = fmaf(c0, __uint_as_float(h0.z & 0xffff0000u), a0[5]);
        a0[6] = fmaf(c0, __uint_as_float(h0.w << 16),         a0[6]);
        a0[7] = fmaf(c0, __uint_as_float(h0.w & 0xffff0000u), a0[7]);
        a1[0] = fmaf(c1, __uint_as_float(h1.x << 16),         a1[0]);
        a1[1] = fmaf(c1, __uint_as_float(h1.x & 0xffff0000u), a1[1]);
        a1[2] = fmaf(c1, __uint_as_float(h1.y << 16),         a1[2]);
        a1[3] = fmaf(c1, __uint_as_float(h1.y & 0xffff0000u), a1[3]);
        a1[4] = fmaf(c1, __uint_as_float(h1.z << 16),         a1[4]);
        a1[5] = fmaf(c1, __uint_as_float(h1.z & 0xffff0000u), a1[5]);
        a1[6] = fmaf(c1, __uint_as_float(h1.w << 16),         a1[6]);
        a1[7] = fmaf(c1, __uint_as_float(h1.w & 0xffff0000u), a1[7]);
    }
#pragma unroll
    for (int m = 8; m < 64; m <<= 1) {
#pragma unroll
        for (int u = 0; u < 8; u++) {
            a0[u] += __shfl_xor(a0[u], m);
            a1[u] += __shfl_xor(a1[u], m);
        }
    }
    if (q < 2) {
        int node = np + q;
        float av[8];
#pragma unroll
        for (int u = 0; u < 8; u++) av[u] = q ? a1[u] : a0[u];
        float di = dinv[node];
        float di2 = di * di;
        uint4 hs = *(const uint4*)(Hbase + (size_t)node * 128 + (f8 << 4));
        float hv[8];
        hv[0] = __uint_as_float(hs.x << 16);
        hv[1] = __uint_as_float(hs.x & 0xffff0000u);
        hv[2] = __uint_as_float(hs.y << 16);
        hv[3] = __uint_as_float(hs.y & 0xffff0000u);
        hv[4] = __uint_as_float(hs.z << 16);
        hv[5] = __uint_as_float(hs.z & 0xffff0000u);
        hv[6] = __uint_as_float(hs.w << 16);
        hv[7] = __uint_as_float(hs.w & 0xffff0000u);
        const float4* bp = (const float4*)(bias + f8 * 8);
        float4 bv0 = bp[0], bv1 = bp[1];
        float r[8];
        r[0] = fmaxf(av[0] + bv0.x + di2 * hv[0], 0.0f);
        r[1] = fmaxf(av[1] + bv0.y + di2 * hv[1], 0.0f);
        r[2] = fmaxf(av[2] + bv0.z + di2 * hv[2], 0.0f);
        r[3] = fmaxf(av[3] + bv0.w + di2 * hv[3], 0.0f);
        r[4] = fmaxf(av[4] + bv1.x + di2 * hv[4], 0.0f);
        r[5] = fmaxf(av[5] + bv1.y + di2 * hv[5], 0.0f);
        r[6] = fmaxf(av[6] + bv1.z + di2 * hv[6], 0.0f);
        r[7] = fmaxf(av[7] + bv1.w + di2 * hv[7], 0.0f);
        __hip_bfloat16 hb[8];
#pragma unroll
        for (int u = 0; u < 8; u++) hb[u] = __float2bfloat16(r[u]);
        *(uint4*)&O[(size_t)node * F + f8 * 8] = *(uint4*)hb;
    }
}

// ---------------- fused mean-pool + final linear (bf16 input) ----------------
__global__ __launch_bounds__(256) void k_pool_linear(const __hip_bfloat16* __restrict__ H,
                                                     const int* __restrict__ gstart,
                                                     const float* __restrict__ Wl,
                                                     const float* __restrict__ bl,
                                                     float* __restrict__ out) {
    int g = blockIdx.x;
    int beg = gstart[g], end = gstart[g + 1];
    int lane = threadIdx.x & 63, wv = threadIdx.x >> 6;
    float acc = 0.0f;
    for (int r = beg + wv; r < end; r += 4)
        acc += __bfloat162float(H[(size_t)r * F + lane]);
    __shared__ float s[4][F];
    s[wv][lane] = acc;
    __syncthreads();
    if (wv == 0) {
        float tot = s[0][lane] + s[1][lane] + s[2][lane] + s[3][lane];
        float cntf = (float)(end - beg);
        float p = tot / fmaxf(cntf, 1.0f);
        for (int c = 0; c < 10; c++) {
            float v = p * Wl[lane * 10 + c];
            for (int off = 32; off; off >>= 1) v += __shfl_down(v, off);
            if (lane == 0) out[g * 10 + c] = v + bl[c];
        }
    }
}

// ---------------- launch ----------------

extern "C" void kernel_launch(void* const* d_in, const int* in_sizes, int n_in,
                              void* d_out, int out_size, void* d_ws, size_t ws_size,
                              hipStream_t stream) {
    const float* x    = (const float*)d_in[0];
    const int*   ei   = (const int*)d_in[1];
    const float* ea   = (const float*)d_in[2];
    const int*   bat  = (const int*)d_in[3];
    const float* W1   = (const float*)d_in[4];
    const float* b1   = (const float*)d_in[5];
    const float* W2   = (const float*)d_in[6];
    const float* b2   = (const float*)d_in[7];
    const float* W3   = (const float*)d_in[8];
    const float* b3   = (const float*)d_in[9];
    const float* Wl   = (const float*)d_in[10];
    const float* bl   = (const float*)d_in[11];
    float* out = (float*)d_out;

    const int* src = ei;
    const int* dst = ei + N_EDGES;

    char* ws = (char*)d_ws;
    size_t off = 0;
    auto carve = [&](size_t bytes) {
        void* p = ws + off;
        off += (bytes + 255) & ~(size_t)255;
        return p;
    };
    float*          dinv    = (float*)carve(N_NODES * 4);
    int*            row_off = (int*)  carve((N_NODES + 1) * 4);
    int2*           esec    = (int2*) carve(((size_t)N_EDGES + 16) * 8);
    __hip_bfloat16* hbuf    = (__hip_bfloat16*)carve((size_t)N_NODES * F * 2);  // 12.8 MB
    __hip_bfloat16* obuf    = (__hip_bfloat16*)carve((size_t)N_NODES * F * 4);  // 25.6 MB carved (build aliases tail)
    int*            gstart  = (int*)  carve((N_GRAPHS + 1) * 4);
    (void)ws_size; (void)in_sizes; (void)n_in; (void)out_size;

    // build-phase scratch: part aliases hbuf (exactly 12.8 MB), hist/btot/base alias obuf tail
    long long* part = (long long*)hbuf;
    char* alias = (char*)obuf + (size_t)N_NODES * F * 2;   // past live bf16 obuf region
    int* hist = (int*)alias;                         alias += (size_t)NCHUNK * NBUCK * 4;  // 613 KB
    int* btot = (int*)alias;                         alias += (NBUCK + 8) * 4;
    int* base = (int*)alias;

    const int EB  = (N_EDGES + 255) / 256 + 1;   // +1 block for the 16 sentinels
    const int GB  = (N_NODES + 127) / 128;       // 782

    k_hist     <<<NCHUNK, 256, 0, stream>>>(dst, hist);
    k_colscan  <<<NBUCK,  256, 0, stream>>>(hist, btot);
    k_bscan    <<<1,      256, 0, stream>>>(btot, base);
    k_partition<<<NCHUNK, 256, 0, stream>>>(src, dst, ea, hist, base, part);
    k_bucket   <<<NBUCK,  256, 0, stream>>>(part, base, dinv, row_off, esec);
    k_coef     <<<EB,     256, 0, stream>>>(esec, dinv);
    k_gstart   <<<2,      256, 0, stream>>>(bat, gstart);

    k_gemm<128, false><<<GB, 256, 0, stream>>>(x, W1, hbuf);
    k_agg<<<N_NODES / 8, 256, 0, stream>>>(hbuf, row_off, esec, dinv, b1, obuf);
    k_gemm<64, true><<<GB, 256, 0, stream>>>(obuf, W2, hbuf);
    k_agg<<<N_NODES / 8, 256, 0, stream>>>(hbuf, row_off, esec, dinv, b2, obuf);
    k_gemm<64, true><<<GB, 256, 0, stream>>>(obuf, W3, hbuf);
    k_agg<<<N_NODES / 8, 256, 0, stream>>>(hbuf, row_off, esec, dinv, b3, obuf);

    k_pool_linear<<<N_GRAPHS, 256, 0, stream>>>(obuf, gstart, Wl, bl, out);
}

// Round 8
// 380.404 us; speedup vs baseline: 2.4110x; 1.0126x over previous
//
#include <hip/hip_runtime.h>
#include <hip/hip_bf16.h>

#define N_NODES  100000
#define N_EDGES  1600000
#define N_GRAPHS 256
#define F 64
#define NBUCK  782    // ceil(N_NODES/128), bucket = dst >> 7
#define CHUNK  4096   // edges per partition chunk
#define NCHUNK 391    // ceil(1.6M/4096)

// ======== atomic-free CSR build: two-level counting sort ========

__global__ __launch_bounds__(1024) void k_hist(const int* __restrict__ dst, int* __restrict__ hist) {
    __shared__ int lh[NBUCK];
    int tid = threadIdx.x, chunk = blockIdx.x;
    for (int j = tid; j < NBUCK; j += 1024) lh[j] = 0;
    __syncthreads();
    int e0 = chunk * CHUNK;
#pragma unroll
    for (int i = 0; i < CHUNK / 1024; i++) {
        int e = e0 + i * 1024 + tid;
        if (e < N_EDGES) atomicAdd(&lh[dst[e] >> 7], 1);
    }
    __syncthreads();
    for (int j = tid; j < NBUCK; j += 1024) hist[chunk * NBUCK + j] = lh[j];
}

// per-bucket column scan over chunks (NCHUNK <= 512: one chunk per thread)
__global__ __launch_bounds__(512) void k_colscan(int* __restrict__ hist, int* __restrict__ btot) {
    __shared__ int ts[512];
    int b = blockIdx.x, tid = threadIdx.x;
    int v = (tid < NCHUNK) ? hist[tid * NBUCK + b] : 0;
    ts[tid] = v;
    __syncthreads();
    int x = v;
    for (int off = 1; off < 512; off <<= 1) {
        int t = (tid >= off) ? ts[tid - off] : 0;
        __syncthreads();
        x += t; ts[tid] = x;
        __syncthreads();
    }
    if (tid < NCHUNK) hist[tid * NBUCK + b] = x - v;
    if (tid == 511) btot[b] = x;
}

__global__ __launch_bounds__(256) void k_bscan(const int* __restrict__ btot, int* __restrict__ base) {
    __shared__ int ts[256];
    int tid = threadIdx.x;
    int v[4], loc[4], run = 0;
#pragma unroll
    for (int k = 0; k < 4; k++) {
        int c = tid * 4 + k;
        v[k] = (c < NBUCK) ? btot[c] : 0;
        loc[k] = run; run += v[k];
    }
    ts[tid] = run;
    __syncthreads();
    int x = run;
    for (int off = 1; off < 256; off <<= 1) {
        int t = (tid >= off) ? ts[tid - off] : 0;
        __syncthreads();
        x += t; ts[tid] = x;
        __syncthreads();
    }
    int texcl = x - run;
#pragma unroll
    for (int k = 0; k < 4; k++) {
        int c = tid * 4 + k;
        if (c < NBUCK) base[c] = texcl + loc[k];
    }
    if (tid == 255) base[NBUCK] = x;
}

__global__ __launch_bounds__(1024) void k_partition(const int* __restrict__ src, const int* __restrict__ dst,
                                                    const float* __restrict__ ew,
                                                    const int* __restrict__ hist, const int* __restrict__ base,
                                                    long long* __restrict__ part) {
    __shared__ int cursor[NBUCK];
    int tid = threadIdx.x, chunk = blockIdx.x;
    for (int j = tid; j < NBUCK; j += 1024) cursor[j] = base[j] + hist[chunk * NBUCK + j];
    __syncthreads();
    int e0 = chunk * CHUNK;
#pragma unroll
    for (int i = 0; i < CHUNK / 1024; i++) {
        int e = e0 + i * 1024 + tid;
        if (e < N_EDGES) {
            int d = dst[e];
            int pos = atomicAdd(&cursor[d >> 7], 1);
            unsigned lo = (unsigned)src[e] | ((unsigned)(d & 127) << 17);
            long long rec = (long long)((unsigned long long)lo |
                            ((unsigned long long)__float_as_uint(ew[e]) << 32));
            part[pos] = rec;
        }
    }
}

// per-bucket: deg (LDS atomics) -> dinv, cnt -> row_off, scatter esec=(src*128, ew*dinv[d])
__global__ __launch_bounds__(256) void k_bucket(const long long* __restrict__ part,
                                                const int* __restrict__ base,
                                                float* __restrict__ dinv_g, int* __restrict__ row_off,
                                                int2* __restrict__ esec) {
    __shared__ float fdeg[128];
    __shared__ float sdinv[128];
    __shared__ int   cnt[128];
    __shared__ int   sc[128];
    __shared__ int   cursor[128];
    int b = blockIdx.x, tid = threadIdx.x;
    if (tid < 128) { fdeg[tid] = 1.0f; cnt[tid] = 0; }   // 1.0 = self-loop weight
    __syncthreads();
    int e0 = base[b], e1 = base[b + 1], ne = e1 - e0;
    for (int k = tid; k < ne; k += 256) {
        long long rec = part[e0 + k];
        int lo = (int)rec;
        int d7 = (lo >> 17) & 127;
        atomicAdd(&fdeg[d7], __uint_as_float((unsigned)(rec >> 32)));
        atomicAdd(&cnt[d7], 1);
    }
    __syncthreads();
    int myc = 0, x = 0;
    if (tid < 128) {
        float dv = rsqrtf(fdeg[tid]);
        sdinv[tid] = dv;
        int node = b * 128 + tid;
        if (node < N_NODES) dinv_g[node] = dv;
        myc = cnt[tid]; x = myc; sc[tid] = x;
    }
    __syncthreads();
    for (int off = 1; off < 128; off <<= 1) {
        int t = (tid < 128 && tid >= off) ? sc[tid - off] : 0;
        __syncthreads();
        if (tid < 128) { x += t; sc[tid] = x; }
        __syncthreads();
    }
    if (tid < 128) {
        int excl = x - myc;
        int node = b * 128 + tid;
        if (node < N_NODES) row_off[node] = e0 + excl;
        cursor[tid] = e0 + excl;
    }
    if (b == 0 && tid == 0) row_off[N_NODES] = N_EDGES;
    __syncthreads();
    for (int k = tid; k < ne; k += 256) {
        long long rec = part[e0 + k];
        int lo = (int)rec;
        int d7 = (lo >> 17) & 127;
        float w = __uint_as_float((unsigned)(rec >> 32));
        int pos = atomicAdd(&cursor[d7], 1);
        esec[pos] = make_int2((lo & 0x1FFFF) << 7, __float_as_int(w * sdinv[d7]));  // byte off: src*128 (bf16 row)
    }
}

// multiply in dinv[src]; zero 16 sentinel entries past N_EDGES (k_agg overrun-reads)
__global__ void k_coef(int2* __restrict__ esec, const float* __restrict__ dinv_g) {
    int e = blockIdx.x * 256 + threadIdx.x;
    if (e < N_EDGES) {
        int2 v = esec[e];
        esec[e] = make_int2(v.x, __float_as_int(__int_as_float(v.y) * dinv_g[((unsigned)v.x) >> 7]));
    } else if (e < N_EDGES + 16) {
        esec[e] = make_int2(0, 0);
    }
}

__global__ void k_gstart(const int* __restrict__ batch, int* gstart) {
    int g = blockIdx.x * 256 + threadIdx.x;
    if (g > N_GRAPHS) return;
    int lo = 0, hi = N_NODES;
    while (lo < hi) {
        int mid = (lo + hi) >> 1;
        if (batch[mid] < g) lo = mid + 1; else hi = mid;
    }
    gstart[g] = lo;
}

// ---------------- GEMM: H[N][64] = X[N][K] @ W[K][64], bf16 output ----------------
template <int K, bool BF16IN>
__global__ __launch_bounds__(256) void k_gemm(const void* __restrict__ Xv,
                                              const float* __restrict__ W,
                                              __hip_bfloat16* __restrict__ H) {
    constexpr int KC = 32;
    constexpr int XP = KC + 4;
    __shared__ float Xs[128 * XP];
    __shared__ float Ws[KC * F];
    const int tid  = threadIdx.x;
    const int fgrp = tid & 15;
    const int ngrp = tid >> 4;
    const int f0   = fgrp * 4;
    const int nb   = blockIdx.x * 128;

    float acc[8][4];
#pragma unroll
    for (int i = 0; i < 8; i++)
#pragma unroll
        for (int j = 0; j < 4; j++) acc[i][j] = 0.0f;

    for (int kc = 0; kc < K; kc += KC) {
        if (kc) __syncthreads();
        if (BF16IN) {
            const unsigned short* X = (const unsigned short*)Xv;
#pragma unroll
            for (int pass = 0; pass < 2; pass++) {
                int idx = tid + pass * 256;
                int r = idx >> 2, q = idx & 3;
                int gr = nb + r; if (gr >= N_NODES) gr = N_NODES - 1;
                uint4 v = *(const uint4*)&X[(size_t)gr * K + kc + q * 8];
                float* dp = &Xs[r * XP + q * 8];
                dp[0] = __uint_as_float(v.x << 16);
                dp[1] = __uint_as_float(v.x & 0xffff0000u);
                dp[2] = __uint_as_float(v.y << 16);
                dp[3] = __uint_as_float(v.y & 0xffff0000u);
                dp[4] = __uint_as_float(v.z << 16);
                dp[5] = __uint_as_float(v.z & 0xffff0000u);
                dp[6] = __uint_as_float(v.w << 16);
                dp[7] = __uint_as_float(v.w & 0xffff0000u);
            }
        } else {
            const float* X = (const float*)Xv;
#pragma unroll
            for (int pass = 0; pass < 4; pass++) {
                int idx = tid + pass * 256;
                int r = idx >> 3, q = idx & 7;
                int gr = nb + r; if (gr >= N_NODES) gr = N_NODES - 1;
                float4 v = *(const float4*)&X[(size_t)gr * K + kc + q * 4];
                *(float4*)&Xs[r * XP + q * 4] = v;
            }
        }
#pragma unroll
        for (int pass = 0; pass < 2; pass++) {
            int idx = tid + pass * 256;
            float4 v = *(const float4*)&W[(size_t)(kc + (idx >> 4)) * F + (idx & 15) * 4];
            *(float4*)&Ws[idx * 4] = v;
        }
        __syncthreads();
#pragma unroll
        for (int k = 0; k < KC; k += 4) {
            float4 wv[4];
#pragma unroll
            for (int kk = 0; kk < 4; kk++)
                wv[kk] = *(const float4*)&Ws[(k + kk) * F + f0];
#pragma unroll
            for (int i = 0; i < 8; i++) {
                float4 xv = *(const float4*)&Xs[(ngrp + 16 * i) * XP + k];
                acc[i][0] = fmaf(xv.x, wv[0].x, acc[i][0]);
                acc[i][0] = fmaf(xv.y, wv[1].x, acc[i][0]);
                acc[i][0] = fmaf(xv.z, wv[2].x, acc[i][0]);
                acc[i][0] = fmaf(xv.w, wv[3].x, acc[i][0]);
                acc[i][1] = fmaf(xv.x, wv[0].y, acc[i][1]);
                acc[i][1] = fmaf(xv.y, wv[1].y, acc[i][1]);
                acc[i][1] = fmaf(xv.z, wv[2].y, acc[i][1]);
                acc[i][1] = fmaf(xv.w, wv[3].y, acc[i][1]);
                acc[i][2] = fmaf(xv.x, wv[0].z, acc[i][2]);
                acc[i][2] = fmaf(xv.y, wv[1].z, acc[i][2]);
                acc[i][2] = fmaf(xv.z, wv[2].z, acc[i][2]);
                acc[i][2] = fmaf(xv.w, wv[3].z, acc[i][2]);
                acc[i][3] = fmaf(xv.x, wv[0].w, acc[i][3]);
                acc[i][3] = fmaf(xv.y, wv[1].w, acc[i][3]);
                acc[i][3] = fmaf(xv.z, wv[2].w, acc[i][3]);
                acc[i][3] = fmaf(xv.w, wv[3].w, acc[i][3]);
            }
        }
    }
#pragma unroll
    for (int i = 0; i < 8; i++) {
        int gn = nb + ngrp + 16 * i;
        if (gn < N_NODES) {
            __hip_bfloat16 hb[4];
            hb[0] = __float2bfloat16(acc[i][0]);
            hb[1] = __float2bfloat16(acc[i][1]);
            hb[2] = __float2bfloat16(acc[i][2]);
            hb[3] = __float2bfloat16(acc[i][3]);
            *(uint2*)&H[(size_t)gn * F + f0] = *(uint2*)hb;
        }
    }
}

// ---------------- aggregation: O = relu(b + dinv^2*H + sum_in c*H[src]) ----------------
// FOUR nodes per wave: 4 independent gather chains -> 32 cache lines in flight.
// Lane = (q = l>>3 edge slot, f8 = l&7 feat group); each lane gathers dwordx4 =
// 8 bf16 feats. Tail: index clamp to zeroed sentinels + per-node coefficient kill.
// Epilogue: shfl_xor reduce over q; lane groups q==0..3 write nodes np..np+3
// (contiguous 512B per wave).
__global__ __launch_bounds__(256) void k_agg(const __hip_bfloat16* __restrict__ H,
                                             const int* __restrict__ row_off,
                                             const int2* __restrict__ esec,
                                             const float* __restrict__ dinv,
                                             const float* __restrict__ bias,
                                             __hip_bfloat16* __restrict__ O) {
    int wv   = threadIdx.x >> 6;
    int lane = threadIdx.x & 63;
    int np   = blockIdx.x * 16 + wv * 4;         // first node of the quad
    int q  = lane >> 3;
    int f8 = lane & 7;
    int r0 = __builtin_amdgcn_readfirstlane(row_off[np]);
    int r1 = __builtin_amdgcn_readfirstlane(row_off[np + 1]);
    int r2 = __builtin_amdgcn_readfirstlane(row_off[np + 2]);
    int r3 = __builtin_amdgcn_readfirstlane(row_off[np + 3]);
    int r4 = __builtin_amdgcn_readfirstlane(row_off[np + 4]);
    const char* Hbase = (const char*)H;

    float a0[8], a1[8], a2[8], a3[8];
#pragma unroll
    for (int u = 0; u < 8; u++) { a0[u] = 0.0f; a1[u] = 0.0f; a2[u] = 0.0f; a3[u] = 0.0f; }

    int l0 = r1 - r0, l1 = r2 - r1, l2 = r3 - r2, l3 = r4 - r3;
    int ml = l0 > l1 ? l0 : l1;
    if (l2 > ml) ml = l2;
    if (l3 > ml) ml = l3;
    int iters = (ml + 7) >> 3;
    int j0 = r0 + q, j1 = r1 + q, j2 = r2 + q, j3 = r3 + q;
    for (int it = 0; it < iters; it++, j0 += 8, j1 += 8, j2 += 8, j3 += 8) {
        int i0 = j0 < N_EDGES ? j0 : N_EDGES;    // clamp into zeroed sentinels
        int i1 = j1 < N_EDGES ? j1 : N_EDGES;
        int i2 = j2 < N_EDGES ? j2 : N_EDGES;
        int i3 = j3 < N_EDGES ? j3 : N_EDGES;
        int2 ev0 = esec[i0];
        int2 ev1 = esec[i1];
        int2 ev2 = esec[i2];
        int2 ev3 = esec[i3];
        float c0 = (j0 < r1) ? __int_as_float(ev0.y) : 0.0f;
        float c1 = (j1 < r2) ? __int_as_float(ev1.y) : 0.0f;
        float c2 = (j2 < r3) ? __int_as_float(ev2.y) : 0.0f;
        float c3 = (j3 < r4) ? __int_as_float(ev3.y) : 0.0f;
        uint4 h0 = *(const uint4*)(Hbase + (unsigned)ev0.x + (f8 << 4));
        uint4 h1 = *(const uint4*)(Hbase + (unsigned)ev1.x + (f8 << 4));
        uint4 h2 = *(const uint4*)(Hbase + (unsigned)ev2.x + (f8 << 4));
        uint4 h3 = *(const uint4*)(Hbase + (unsigned)ev3.x + (f8 << 4));
        a0[0] = fmaf(c0, __uint_as_float(h0.x << 16),         a0[0]);
        a0[1] = fmaf(c0, __uint_as_float(h0.x & 0xffff0000u), a0[1]);
        a0[2] = fmaf(c0, __uint_as_float(h0.y << 16),         a0[2]);
        a0[3] = fmaf(c0, __uint_as_float(h0.y & 0xffff0000u), a0[3]);
        a0[4] = fmaf(c0, __uint_as_float(h0.z << 16),         a0[4]);
        a0[5] = fmaf(c0, __uint_as_float(h0.z & 0xffff0000u), a0[5]);
        a0[6] = fmaf(c0, __uint_as_float(h0.w << 16),         a0[6]);
        a0[7] = fmaf(c0, __uint_as_float(h0.w & 0xffff0000u), a0[7]);
        a1[0] = fmaf(c1, __uint_as_float(h1.x << 16),         a1[0]);
        a1[1] = fmaf(c1, __uint_as_float(h1.x & 0xffff0000u), a1[1]);
        a1[2] = fmaf(c1, __uint_as_float(h1.y << 16),         a1[2]);
        a1[3] = fmaf(c1, __uint_as_float(h1.y & 0xffff0000u), a1[3]);
        a1[4] = fmaf(c1, __uint_as_float(h1.z << 16),         a1[4]);
        a1[5] = fmaf(c1, __uint_as_float(h1.z & 0xffff0000u), a1[5]);
        a1[6] = fmaf(c1, __uint_as_float(h1.w << 16),         a1[6]);
        a1[7] = fmaf(c1, __uint_as_float(h1.w & 0xffff0000u), a1[7]);
        a2[0] = fmaf(c2, __uint_as_float(h2.x << 16),         a2[0]);
        a2[1] = fmaf(c2, __uint_as_float(h2.x & 0xffff0000u), a2[1]);
        a2[2] = fmaf(c2, __uint_as_float(h2.y << 16),         a2[2]);
        a2[3] = fmaf(c2, __uint_as_float(h2.y & 0xffff0000u), a2[3]);
        a2[4] = fmaf(c2, __uint_as_float(h2.z << 16),         a2[4]);
        a2[5] = fmaf(c2, __uint_as_float(h2.z & 0xffff0000u), a2[5]);
        a2[6] = fmaf(c2, __uint_as_float(h2.w << 16),         a2[6]);
        a2[7] = fmaf(c2, __uint_as_float(h2.w & 0xffff0000u), a2[7]);
        a3[0] = fmaf(c3, __uint_as_float(h3.x << 16),         a3[0]);
        a3[1] = fmaf(c3, __uint_as_float(h3.x & 0xffff0000u), a3[1]);
        a3[2] = fmaf(c3, __uint_as_float(h3.y << 16),         a3[2]);
        a3[3] = fmaf(c3, __uint_as_float(h3.y & 0xffff0000u), a3[3]);
        a3[4] = fmaf(c3, __uint_as_float(h3.z << 16),         a3[4]);
        a3[5] = fmaf(c3, __uint_as_float(h3.z & 0xffff0000u), a3[5]);
        a3[6] = fmaf(c3, __uint_as_float(h3.w << 16),         a3[6]);
        a3[7] = fmaf(c3, __uint_as_float(h3.w & 0xffff0000u), a3[7]);
    }
#pragma unroll
    for (int m = 8; m < 64; m <<= 1) {
#pragma unroll
        for (int u = 0; u < 8; u++) {
            a0[u] += __shfl_xor(a0[u], m);
            a1[u] += __shfl_xor(a1[u], m);
            a2[u] += __shfl_xor(a2[u], m);
            a3[u] += __shfl_xor(a3[u], m);
        }
    }
    if (q < 4) {
        int node = np + q;
        float av[8];
#pragma unroll
        for (int u = 0; u < 8; u++) {
            float t01 = (q & 1) ? a1[u] : a0[u];
            float t23 = (q & 1) ? a3[u] : a2[u];
            av[u] = (q & 2) ? t23 : t01;
        }
        float di = dinv[node];
        float di2 = di * di;
        uint4 hs = *(const uint4*)(Hbase + (size_t)node * 128 + (f8 << 4));
        float hv[8];
        hv[0] = __uint_as_float(hs.x << 16);
        hv[1] = __uint_as_float(hs.x & 0xffff0000u);
        hv[2] = __uint_as_float(hs.y << 16);
        hv[3] = __uint_as_float(hs.y & 0xffff0000u);
        hv[4] = __uint_as_float(hs.z << 16);
        hv[5] = __uint_as_float(hs.z & 0xffff0000u);
        hv[6] = __uint_as_float(hs.w << 16);
        hv[7] = __uint_as_float(hs.w & 0xffff0000u);
        const float4* bp = (const float4*)(bias + f8 * 8);
        float4 bv0 = bp[0], bv1 = bp[1];
        float r[8];
        r[0] = fmaxf(av[0] + bv0.x + di2 * hv[0], 0.0f);
        r[1] = fmaxf(av[1] + bv0.y + di2 * hv[1], 0.0f);
        r[2] = fmaxf(av[2] + bv0.z + di2 * hv[2], 0.0f);
        r[3] = fmaxf(av[3] + bv0.w + di2 * hv[3], 0.0f);
        r[4] = fmaxf(av[4] + bv1.x + di2 * hv[4], 0.0f);
        r[5] = fmaxf(av[5] + bv1.y + di2 * hv[5], 0.0f);
        r[6] = fmaxf(av[6] + bv1.z + di2 * hv[6], 0.0f);
        r[7] = fmaxf(av[7] + bv1.w + di2 * hv[7], 0.0f);
        __hip_bfloat16 hb[8];
#pragma unroll
        for (int u = 0; u < 8; u++) hb[u] = __float2bfloat16(r[u]);
        *(uint4*)&O[(size_t)node * F + f8 * 8] = *(uint4*)hb;
    }
}

// ---------------- fused mean-pool + final linear (bf16 input) ----------------
__global__ __launch_bounds__(256) void k_pool_linear(const __hip_bfloat16* __restrict__ H,
                                                     const int* __restrict__ gstart,
                                                     const float* __restrict__ Wl,
                                                     const float* __restrict__ bl,
                                                     float* __restrict__ out) {
    int g = blockIdx.x;
    int beg = gstart[g], end = gstart[g + 1];
    int lane = threadIdx.x & 63, wv = threadIdx.x >> 6;
    float acc = 0.0f;
    for (int r = beg + wv; r < end; r += 4)
        acc += __bfloat162float(H[(size_t)r * F + lane]);
    __shared__ float s[4][F];
    s[wv][lane] = acc;
    __syncthreads();
    if (wv == 0) {
        float tot = s[0][lane] + s[1][lane] + s[2][lane] + s[3][lane];
        float cntf = (float)(end - beg);
        float p = tot / fmaxf(cntf, 1.0f);
        for (int c = 0; c < 10; c++) {
            float v = p * Wl[lane * 10 + c];
            for (int off = 32; off; off >>= 1) v += __shfl_down(v, off);
            if (lane == 0) out[g * 10 + c] = v + bl[c];
        }
    }
}

// ---------------- launch ----------------

extern "C" void kernel_launch(void* const* d_in, const int* in_sizes, int n_in,
                              void* d_out, int out_size, void* d_ws, size_t ws_size,
                              hipStream_t stream) {
    const float* x    = (const float*)d_in[0];
    const int*   ei   = (const int*)d_in[1];
    const float* ea   = (const float*)d_in[2];
    const int*   bat  = (const int*)d_in[3];
    const float* W1   = (const float*)d_in[4];
    const float* b1   = (const float*)d_in[5];
    const float* W2   = (const float*)d_in[6];
    const float* b2   = (const float*)d_in[7];
    const float* W3   = (const float*)d_in[8];
    const float* b3   = (const float*)d_in[9];
    const float* Wl   = (const float*)d_in[10];
    const float* bl   = (const float*)d_in[11];
    float* out = (float*)d_out;

    const int* src = ei;
    const int* dst = ei + N_EDGES;

    char* ws = (char*)d_ws;
    size_t off = 0;
    auto carve = [&](size_t bytes) {
        void* p = ws + off;
        off += (bytes + 255) & ~(size_t)255;
        return p;
    };
    float*          dinv    = (float*)carve(N_NODES * 4);
    int*            row_off = (int*)  carve((N_NODES + 1) * 4);
    int2*           esec    = (int2*) carve(((size_t)N_EDGES + 16) * 8);
    __hip_bfloat16* hbuf    = (__hip_bfloat16*)carve((size_t)N_NODES * F * 2);  // 12.8 MB
    __hip_bfloat16* obuf    = (__hip_bfloat16*)carve((size_t)N_NODES * F * 4);  // 25.6 MB carved (build aliases tail)
    int*            gstart  = (int*)  carve((N_GRAPHS + 1) * 4);
    (void)ws_size; (void)in_sizes; (void)n_in; (void)out_size;

    // build-phase scratch: part aliases hbuf (exactly 12.8 MB), hist/btot/base alias obuf tail
    long long* part = (long long*)hbuf;
    char* alias = (char*)obuf + (size_t)N_NODES * F * 2;   // past live bf16 obuf region
    int* hist = (int*)alias;                         alias += (size_t)NCHUNK * NBUCK * 4;  // 1.22 MB
    int* btot = (int*)alias;                         alias += (NBUCK + 8) * 4;
    int* base = (int*)alias;

    const int EB  = (N_EDGES + 255) / 256 + 1;   // +1 block for the 16 sentinels
    const int GB  = (N_NODES + 127) / 128;       // 782

    k_hist     <<<NCHUNK, 1024, 0, stream>>>(dst, hist);
    k_colscan  <<<NBUCK,  512,  0, stream>>>(hist, btot);
    k_bscan    <<<1,      256,  0, stream>>>(btot, base);
    k_partition<<<NCHUNK, 1024, 0, stream>>>(src, dst, ea, hist, base, part);
    k_bucket   <<<NBUCK,  256,  0, stream>>>(part, base, dinv, row_off, esec);
    k_coef     <<<EB,     256,  0, stream>>>(esec, dinv);
    k_gstart   <<<2,      256,  0, stream>>>(bat, gstart);

    k_gemm<128, false><<<GB, 256, 0, stream>>>(x, W1, hbuf);
    k_agg<<<N_NODES / 16, 256, 0, stream>>>(hbuf, row_off, esec, dinv, b1, obuf);
    k_gemm<64, true><<<GB, 256, 0, stream>>>(obuf, W2, hbuf);
    k_agg<<<N_NODES / 16, 256, 0, stream>>>(hbuf, row_off, esec, dinv, b2, obuf);
    k_gemm<64, true><<<GB, 256, 0, stream>>>(obuf, W3, hbuf);
    k_agg<<<N_NODES / 16, 256, 0, stream>>>(hbuf, row_off, esec, dinv, b3, obuf);

    k_pool_linear<<<N_GRAPHS, 256, 0, stream>>>(obuf, gstart, Wl, bl, out);
}